// Round 5
// baseline (152.900 us; speedup 1.0000x reference)
//
#include <hip/hip_runtime.h>
#include <math.h>

#define NN 325
#define BT 96
#define NROWS (BT * NN)   // 31200
// fold softmax scale and log2(e) into q: exp(s/sqrt8) == exp2(s * SCL)
#define SCL (0.35355339059327373f * 1.4426950408889634f)
#define QKV_BLKS ((NROWS + 63) / 64)        // 488
#define PREP_ITEMS (11 * NN + 8192)         // 3575 masks + 8192 wab = 11767
#define PREP_BLKS ((PREP_ITEMS + 511) / 512) // 23
#define TOT_BLKS (QKV_BLKS + PREP_BLKS)     // 511

typedef _Float16 half_t;
typedef half_t half8_t __attribute__((ext_vector_type(8)));
typedef half_t half4_t __attribute__((ext_vector_type(4)));
typedef half_t half2_t __attribute__((ext_vector_type(2)));
typedef float float4_t __attribute__((ext_vector_type(4)));

__device__ __forceinline__ float gelu_f(float x) {
    return 0.5f * x * (1.0f + erff(x * 0.70710678118654752f));
}

#define XS 136   // half stride per 128-k row (qkv)
#define PS 72    // half stride per 64-k row (proj)

// Stage a 64x128 f32 weight matrix into LDS as f16 (layout identical to the
// old prep-produced f16 copy: row c, k-group g of 8).
__device__ __forceinline__ void qkv_stage_wf(const float* __restrict__ src,
                                             half_t* dst, int tid)
{
    #pragma unroll
    for (int idx = tid; idx < 1024; idx += 512) {
        int c = idx >> 4, g = idx & 15;
        const float4* s4 = (const float4*)&src[c * 128 + g * 8];
        float4 a = s4[0], b = s4[1];
        half8_t h;
        h[0] = (half_t)a.x; h[1] = (half_t)a.y;
        h[2] = (half_t)a.z; h[3] = (half_t)a.w;
        h[4] = (half_t)b.x; h[5] = (half_t)b.y;
        h[6] = (half_t)b.z; h[7] = (half_t)b.w;
        *(half8_t*)&dst[c * XS + g * 8] = h;
    }
}

__device__ __forceinline__ void qkv_compute(
    const half_t* x16, const half_t* wb, const float* __restrict__ b,
    half_t* __restrict__ outp, float oscale,
    int row0, int rbase, int ch, int l15, int quad)
{
    float4_t acc[2];
    #pragma unroll
    for (int cc = 0; cc < 2; ++cc) {
        float bias = b[(ch * 2 + cc) * 16 + l15];
        acc[cc] = (float4_t){bias, bias, bias, bias};
    }
    #pragma unroll
    for (int kk = 0; kk < 8; ++kk) {
        half4_t a = *(const half4_t*)&x16[(rbase + l15) * XS + kk * 16 + quad * 4];
        #pragma unroll
        for (int cc = 0; cc < 2; ++cc) {
            half4_t bf = *(const half4_t*)
                &wb[((ch * 2 + cc) * 16 + l15) * XS + kk * 16 + quad * 4];
            acc[cc] = __builtin_amdgcn_mfma_f32_16x16x16f16(a, bf, acc[cc], 0, 0, 0);
        }
    }
    #pragma unroll
    for (int cc = 0; cc < 2; ++cc) {
        #pragma unroll
        for (int rr = 0; rr < 4; ++rr) {
            int R = row0 + rbase + quad * 4 + rr;
            if (R < NROWS)
                outp[R * 64 + (ch * 2 + cc) * 16 + l15] =
                    (half_t)(gelu_f(acc[cc][rr]) * oscale);
        }
    }
}

// ---------------------------------------------------------------------------
// Kernel 1: q/k/v = gelu(concat(X,STE) @ W.T + b) via f16 MFMA.
// Blocks [0,488): one 64-row tile each; weights converted f32->f16 inline.
// Blocks [488,511): prep work (adj bitmasks + wab f16) consumed by the
// NEXT launches (attn / proj).
// ---------------------------------------------------------------------------
__global__ __launch_bounds__(512) void qkv_kernel(
    const float* __restrict__ X, const float* __restrict__ STE,
    const int* __restrict__ adj,
    const float* __restrict__ W7, const float* __restrict__ b7,
    const float* __restrict__ W8, const float* __restrict__ b8,
    const float* __restrict__ W9, const float* __restrict__ b9,
    const float* __restrict__ W10, const float* __restrict__ W11,
    half_t* __restrict__ q, half_t* __restrict__ k, half_t* __restrict__ v,
    unsigned int* __restrict__ packedT, half_t* __restrict__ wab)
{
    const int tid = threadIdx.x;
    const int bx  = blockIdx.x;

    if (bx >= QKV_BLKS) {
        // ------- prep tail blocks: masks + W10/W11 f16 conversion ---------
        int idx = (bx - QKV_BLKS) * 512 + tid;
        if (idx < 11 * NN) {
            int w = idx / NN, n = idx - w * NN;
            unsigned int bits = 0u;
            #pragma unroll 8
            for (int j = 0; j < 32; ++j) {
                int m = w * 32 + j;
                if (m < NN && adj[n * NN + m] > 0) bits |= (1u << j);
            }
            packedT[w * NN + n] = bits;
        } else if (idx < PREP_ITEMS) {
            int i = idx - 11 * NN;
            int p = i >> 12, r = i & 4095;
            wab[i] = (half_t)(p ? W11[r] : W10[r]);
        }
        return;
    }

    __shared__ __attribute__((aligned(16))) half_t x16[64 * XS];
    __shared__ __attribute__((aligned(16))) half_t wbuf[2][64 * XS];
    const int row0 = bx * 64;

    // stage x = concat(X, STE) -> f16
    #pragma unroll
    for (int idx = tid; idx < 2048; idx += 512) {
        int r = idx >> 5, c4 = idx & 31;
        int R = row0 + r;
        float4 f = {0.f, 0.f, 0.f, 0.f};
        if (R < NROWS)
            f = (c4 < 16) ? *(const float4*)(X + R * 64 + c4 * 4)
                          : *(const float4*)(STE + R * 64 + (c4 - 16) * 4);
        half4_t hv;
        hv[0] = (half_t)f.x; hv[1] = (half_t)f.y;
        hv[2] = (half_t)f.z; hv[3] = (half_t)f.w;
        *(half4_t*)&x16[r * XS + c4 * 4] = hv;
    }
    qkv_stage_wf(W7, wbuf[0], tid);          // W7 (f32 -> f16 inline)
    __syncthreads();

    const int lane = tid & 63, wv = tid >> 6;
    const int l15 = lane & 15, quad = lane >> 4;
    const int rbase = (wv & 3) * 16, ch = wv >> 2;

    qkv_stage_wf(W8, wbuf[1], tid);          // W8 (overlaps phase 0)
    qkv_compute(x16, wbuf[0], b7, q, SCL, row0, rbase, ch, l15, quad);
    __syncthreads();

    qkv_stage_wf(W9, wbuf[0], tid);          // W9 (overlaps phase 1)
    qkv_compute(x16, wbuf[1], b8, k, 1.0f, row0, rbase, ch, l15, quad);
    __syncthreads();

    qkv_compute(x16, wbuf[0], b9, v, 1.0f, row0, rbase, ch, l15, quad);
}

// ---------------------------------------------------------------------------
// Kernel 2: MFMA flash attention, SINGLE-PASS.
// Score fragments kept in registers (sarr[21] = 84 VGPR, fully unrolled ->
// no scratch). Removes pass A's 21 redundant MFMAs + 21 K16 LDS sweeps per
// q-tile (63 -> 42 MFMAs/tile). VGPR ~150 still allows 3 waves/SIMD = same
// 24 waves/CU occupancy (grid-limited at 3 blocks/CU x 8 waves).
// ---------------------------------------------------------------------------
__global__ __launch_bounds__(512) void attn_kernel(
    const half_t* __restrict__ q16g, const half_t* __restrict__ k16g,
    const half_t* __restrict__ v16g, const unsigned int* __restrict__ packedT,
    half_t* __restrict__ ao)
{
    __shared__ __attribute__((aligned(16))) half_t K16[336 * 20]; // [m][d0..15,pad]
    __shared__ __attribute__((aligned(16))) half_t VT16[16 * 344];// [c][m]
    const int tid = threadIdx.x;
    const int h = blockIdx.x, bt = blockIdx.y;
    const long base = (long)(bt * NN) * 64 + h * 8;

    const half4_t z4 = {(half_t)0.f, (half_t)0.f, (half_t)0.f, (half_t)0.f};

    // zero VT16, then ones row c=8
    for (int idx = tid; idx < 16 * 344 / 2; idx += 512)
        ((half2_t*)VT16)[idx] = (half2_t)(half_t)0.f;
    __syncthreads();
    for (int i = tid; i < 344; i += 512)
        VT16[8 * 344 + i] = (half_t)1.0f;

    // stage K rows (stride 20, d 8..15 zero)
    for (int r = tid; r < 336; r += 512) {
        half4_t ka = z4, kbv = z4;
        if (r < NN) {
            ka  = *(const half4_t*)(k16g + base + r * 64);
            kbv = *(const half4_t*)(k16g + base + r * 64 + 4);
        }
        *(half4_t*)&K16[r * 20]      = ka;
        *(half4_t*)&K16[r * 20 + 4]  = kbv;
        *(half4_t*)&K16[r * 20 + 8]  = z4;
        *(half4_t*)&K16[r * 20 + 12] = z4;
    }

    // stage V transposed via m-pair half2 writes (rows c = 0..7)
    for (int mp = tid; mp < 168; mp += 512) {
        int m0 = 2 * mp, m1 = 2 * mp + 1;
        half4_t v0a = z4, v0b = z4, v1a = z4, v1b = z4;
        if (m0 < NN) {
            v0a = *(const half4_t*)(v16g + base + m0 * 64);
            v0b = *(const half4_t*)(v16g + base + m0 * 64 + 4);
        }
        if (m1 < NN) {
            v1a = *(const half4_t*)(v16g + base + m1 * 64);
            v1b = *(const half4_t*)(v16g + base + m1 * 64 + 4);
        }
        #pragma unroll
        for (int c = 0; c < 4; ++c) {
            half2_t p0; p0[0] = v0a[c]; p0[1] = v1a[c];
            half2_t p1; p1[0] = v0b[c]; p1[1] = v1b[c];
            *(half2_t*)&VT16[c * 344 + 2 * mp]       = p0;
            *(half2_t*)&VT16[(c + 4) * 344 + 2 * mp] = p1;
        }
    }
    __syncthreads();

    const int lane = tid & 63;
    const int wv   = tid >> 6;     // 0..7
    const int l15  = lane & 15;
    const int quad = lane >> 4;
    const int qsh  = quad * 4;

    for (int t = wv; t < 21; t += 8) {
        const int n  = t * 16 + l15;
        const int nq = (n < NN) ? n : (NN - 1);   // clamp for global reads

        half4_t qf = z4;
        if (quad < 2)
            qf = *(const half4_t*)(q16g + base + (long)nq * 64 + qsh);

        // mask words: latency hides under the score MFMAs
        unsigned int mb[11];
        #pragma unroll
        for (int w = 0; w < 11; ++w) mb[w] = packedT[w * NN + nq];

        // single score sweep: s fragments stay in registers
        float4_t sarr[21];
        float rm = 0.0f;
        #pragma unroll
        for (int mt = 0; mt < 21; ++mt) {
            half4_t kf = *(const half4_t*)&K16[(mt * 16 + l15) * 20 + qsh];
            sarr[mt] = __builtin_amdgcn_mfma_f32_16x16x16f16(
                kf, qf, (float4_t){0.f, 0.f, 0.f, 0.f}, 0, 0, 0);
            rm = fmaxf(rm, fmaxf(fmaxf(sarr[mt][0], sarr[mt][1]),
                                 fmaxf(sarr[mt][2], sarr[mt][3])));
        }
        rm = fmaxf(rm, __shfl_xor(rm, 16, 64));
        rm = fmaxf(rm, __shfl_xor(rm, 32, 64));

        // p = exp2(s - rm) masked; sum via ones-row (VT row c=8)
        float4_t acc = {0.f, 0.f, 0.f, 0.f};
        #pragma unroll
        for (int mt = 0; mt < 21; ++mt) {
            unsigned int sh = mb[mt >> 1] >> (((mt & 1) << 4) + qsh);
            float p0 = (sh & 1u) ? __builtin_amdgcn_exp2f(sarr[mt][0] - rm) : 0.f;
            float p1 = (sh & 2u) ? __builtin_amdgcn_exp2f(sarr[mt][1] - rm) : 0.f;
            float p2 = (sh & 4u) ? __builtin_amdgcn_exp2f(sarr[mt][2] - rm) : 0.f;
            float p3 = (sh & 8u) ? __builtin_amdgcn_exp2f(sarr[mt][3] - rm) : 0.f;
            half4_t pf;
            pf[0] = (half_t)p0; pf[1] = (half_t)p1;
            pf[2] = (half_t)p2; pf[3] = (half_t)p3;
            half4_t vf = *(const half4_t*)&VT16[l15 * 344 + mt * 16 + qsh];
            acc = __builtin_amdgcn_mfma_f32_16x16x16f16(vf, pf, acc, 0, 0, 0);
        }

        // sum for row n lives in lane (quad=2).acc[0]  (ones row c=8)
        float sum = __shfl(acc[0], 32 + l15, 64);

        if (quad < 2 && n < NN) {
            float inv = 1.0f / sum;
            half4_t o;
            o[0] = (half_t)(acc[0] * inv); o[1] = (half_t)(acc[1] * inv);
            o[2] = (half_t)(acc[2] * inv); o[3] = (half_t)(acc[3] * inv);
            *(half4_t*)(ao + base + (long)n * 64 + qsh) = o;
        }
    }
}

// ---------------------------------------------------------------------------
// Kernel 3: out = gelu(ao @ W10.T + b10) @ W11.T + b11 (verbatim baseline).
// ---------------------------------------------------------------------------
__global__ __launch_bounds__(512) void proj_kernel(
    const half_t* __restrict__ ao, const half_t* __restrict__ wab,
    const float* __restrict__ b10, const float* __restrict__ b11,
    float* __restrict__ out)
{
    __shared__ __attribute__((aligned(16))) half_t a16[64 * PS];
    __shared__ __attribute__((aligned(16))) half_t wA[64 * PS];
    __shared__ __attribute__((aligned(16))) half_t wB[64 * PS];
    __shared__ __attribute__((aligned(16))) half_t h16[64 * PS];
    const int tid  = threadIdx.x;
    const int row0 = blockIdx.x * 64;

    for (int idx = tid; idx < 512; idx += 512) {
        int r = idx >> 3, c8 = idx & 7;
        int R = row0 + r;
        uint4 u = {0u, 0u, 0u, 0u};
        if (R < NROWS) u = *(const uint4*)(ao + (long)R * 64 + c8 * 8);
        *(uint4*)&a16[r * PS + c8 * 8] = u;
        *(uint4*)&wA[r * PS + c8 * 8] = *(const uint4*)&wab[r * 64 + c8 * 8];
        *(uint4*)&wB[r * PS + c8 * 8] = *(const uint4*)&wab[4096 + r * 64 + c8 * 8];
    }
    __syncthreads();

    const int lane = tid & 63, wv = tid >> 6;
    const int l15 = lane & 15, quad = lane >> 4;
    const int rbase = (wv & 3) * 16, ch = wv >> 2;

    // stage 1: h = gelu(a @ W10.T + b10)
    float4_t acc[2];
    #pragma unroll
    for (int cc = 0; cc < 2; ++cc) {
        float bias = b10[(ch * 2 + cc) * 16 + l15];
        acc[cc] = (float4_t){bias, bias, bias, bias};
    }
    #pragma unroll
    for (int kk = 0; kk < 4; ++kk) {
        half4_t a = *(const half4_t*)&a16[(rbase + l15) * PS + kk * 16 + quad * 4];
        #pragma unroll
        for (int cc = 0; cc < 2; ++cc) {
            half4_t bf = *(const half4_t*)
                &wA[((ch * 2 + cc) * 16 + l15) * PS + kk * 16 + quad * 4];
            acc[cc] = __builtin_amdgcn_mfma_f32_16x16x16f16(a, bf, acc[cc], 0, 0, 0);
        }
    }
    #pragma unroll
    for (int cc = 0; cc < 2; ++cc) {
        #pragma unroll
        for (int rr = 0; rr < 4; ++rr)
            h16[(rbase + quad * 4 + rr) * PS + (ch * 2 + cc) * 16 + l15] =
                (half_t)gelu_f(acc[cc][rr]);
    }
    __syncthreads();

    // stage 2: out = h @ W11.T + b11
    #pragma unroll
    for (int cc = 0; cc < 2; ++cc) {
        float bias = b11[(ch * 2 + cc) * 16 + l15];
        acc[cc] = (float4_t){bias, bias, bias, bias};
    }
    #pragma unroll
    for (int kk = 0; kk < 4; ++kk) {
        half4_t a = *(const half4_t*)&h16[(rbase + l15) * PS + kk * 16 + quad * 4];
        #pragma unroll
        for (int cc = 0; cc < 2; ++cc) {
            half4_t bf = *(const half4_t*)
                &wB[((ch * 2 + cc) * 16 + l15) * PS + kk * 16 + quad * 4];
            acc[cc] = __builtin_amdgcn_mfma_f32_16x16x16f16(a, bf, acc[cc], 0, 0, 0);
        }
    }
    #pragma unroll
    for (int cc = 0; cc < 2; ++cc) {
        #pragma unroll
        for (int rr = 0; rr < 4; ++rr) {
            int R = row0 + rbase + quad * 4 + rr;
            if (R < NROWS)
                out[R * 64 + (ch * 2 + cc) * 16 + l15] = acc[cc][rr];
        }
    }
}

extern "C" void kernel_launch(void* const* d_in, const int* in_sizes, int n_in,
                              void* d_out, int out_size, void* d_ws, size_t ws_size,
                              hipStream_t stream) {
    const float* X   = (const float*)d_in[0];
    const float* STE = (const float*)d_in[1];
    const int*   adj = (const int*)d_in[2];
    const float* W7  = (const float*)d_in[3];
    const float* b7  = (const float*)d_in[4];
    const float* W8  = (const float*)d_in[5];
    const float* b8  = (const float*)d_in[6];
    const float* W9  = (const float*)d_in[7];
    const float* b9  = (const float*)d_in[8];
    const float* W10 = (const float*)d_in[9];
    const float* b10 = (const float*)d_in[10];
    const float* W11 = (const float*)d_in[11];
    const float* b11 = (const float*)d_in[12];

    char* wsb = (char*)d_ws;
    const long S = (long)NROWS * 64;           // 1,996,800 elements
    half_t* qb = (half_t*)wsb;
    half_t* kb = qb + S;
    half_t* vb = qb + 2 * S;
    half_t* ab = qb + 3 * S;
    unsigned int* pk = (unsigned int*)(wsb + 4 * S * sizeof(half_t));
    half_t* wab = (half_t*)(wsb + 4 * S * sizeof(half_t) + 16384);

    qkv_kernel<<<dim3(TOT_BLKS), 512, 0, stream>>>(
        X, STE, adj, W7, b7, W8, b8, W9, b9, W10, W11,
        qb, kb, vb, pk, wab);
    attn_kernel<<<dim3(8, BT), 512, 0, stream>>>(qb, kb, vb, pk, ab);
    proj_kernel<<<dim3((NROWS + 63) / 64), 512, 0, stream>>>(
        ab, wab, b10, b11, (float*)d_out);
}

// Round 6
// 147.983 us; speedup vs baseline: 1.0332x; 1.0332x over previous
//
#include <hip/hip_runtime.h>
#include <math.h>

#define NN 325
#define BT 96
#define NROWS (BT * NN)   // 31200
// fold softmax scale and log2(e) into q: exp(s/sqrt8) == exp2(s * SCL)
#define SCL (0.35355339059327373f * 1.4426950408889634f)
#define QKV_BLKS ((NROWS + 63) / 64)        // 488
#define PREP_ITEMS (11 * NN + 8192)         // 3575 masks + 8192 wab = 11767
#define PREP_BLKS ((PREP_ITEMS + 511) / 512) // 23
#define TOT_BLKS (QKV_BLKS + PREP_BLKS)     // 511

typedef _Float16 half_t;
typedef half_t half8_t __attribute__((ext_vector_type(8)));
typedef half_t half4_t __attribute__((ext_vector_type(4)));
typedef half_t half2_t __attribute__((ext_vector_type(2)));
typedef float float4_t __attribute__((ext_vector_type(4)));

__device__ __forceinline__ float gelu_f(float x) {
    return 0.5f * x * (1.0f + erff(x * 0.70710678118654752f));
}

#define XS 136   // half stride per 128-k row (qkv)
#define PS 72    // half stride per 64-k row (proj)

// Stage a 64x128 f32 weight matrix into LDS as f16.
__device__ __forceinline__ void qkv_stage_wf(const float* __restrict__ src,
                                             half_t* dst, int tid)
{
    #pragma unroll
    for (int idx = tid; idx < 1024; idx += 512) {
        int c = idx >> 4, g = idx & 15;
        const float4* s4 = (const float4*)&src[c * 128 + g * 8];
        float4 a = s4[0], b = s4[1];
        half8_t h;
        h[0] = (half_t)a.x; h[1] = (half_t)a.y;
        h[2] = (half_t)a.z; h[3] = (half_t)a.w;
        h[4] = (half_t)b.x; h[5] = (half_t)b.y;
        h[6] = (half_t)b.z; h[7] = (half_t)b.w;
        *(half8_t*)&dst[c * XS + g * 8] = h;
    }
}

__device__ __forceinline__ void qkv_compute(
    const half_t* x16, const half_t* wb, const float* __restrict__ b,
    half_t* __restrict__ outp, float oscale,
    int row0, int rbase, int ch, int l15, int quad)
{
    float4_t acc[2];
    #pragma unroll
    for (int cc = 0; cc < 2; ++cc) {
        float bias = b[(ch * 2 + cc) * 16 + l15];
        acc[cc] = (float4_t){bias, bias, bias, bias};
    }
    #pragma unroll
    for (int kk = 0; kk < 8; ++kk) {
        half4_t a = *(const half4_t*)&x16[(rbase + l15) * XS + kk * 16 + quad * 4];
        #pragma unroll
        for (int cc = 0; cc < 2; ++cc) {
            half4_t bf = *(const half4_t*)
                &wb[((ch * 2 + cc) * 16 + l15) * XS + kk * 16 + quad * 4];
            acc[cc] = __builtin_amdgcn_mfma_f32_16x16x16f16(a, bf, acc[cc], 0, 0, 0);
        }
    }
    #pragma unroll
    for (int cc = 0; cc < 2; ++cc) {
        #pragma unroll
        for (int rr = 0; rr < 4; ++rr) {
            int R = row0 + rbase + quad * 4 + rr;
            if (R < NROWS)
                outp[R * 64 + (ch * 2 + cc) * 16 + l15] =
                    (half_t)(gelu_f(acc[cc][rr]) * oscale);
        }
    }
}

// ---------------------------------------------------------------------------
// Kernel 1: q/k/v = gelu(concat(X,STE) @ W.T + b) via f16 MFMA.
// SINGLE-SYNC structure: stage x + W7 + W8 into LDS, W9 fragment straight
// into registers (L2-hot; identical f32->f16 cast path), ONE __syncthreads,
// then 48 MFMAs + 3 gelu/store phases as one unbroken stream per wave.
// (r5 lesson: this kernel class is latency-bound; removing 2 of 3 barrier
// drains matters more than work micro-opts.)
// Blocks [488,511): prep work (adj bitmasks + wab f16) for later launches.
// ---------------------------------------------------------------------------
__global__ __launch_bounds__(512) void qkv_kernel(
    const float* __restrict__ X, const float* __restrict__ STE,
    const int* __restrict__ adj,
    const float* __restrict__ W7, const float* __restrict__ b7,
    const float* __restrict__ W8, const float* __restrict__ b8,
    const float* __restrict__ W9, const float* __restrict__ b9,
    const float* __restrict__ W10, const float* __restrict__ W11,
    half_t* __restrict__ q, half_t* __restrict__ k, half_t* __restrict__ v,
    unsigned int* __restrict__ packedT, half_t* __restrict__ wab)
{
    const int tid = threadIdx.x;
    const int bx  = blockIdx.x;

    if (bx >= QKV_BLKS) {
        // ------- prep tail blocks: masks + W10/W11 f16 conversion ---------
        int idx = (bx - QKV_BLKS) * 512 + tid;
        if (idx < 11 * NN) {
            int w = idx / NN, n = idx - w * NN;
            unsigned int bits = 0u;
            #pragma unroll 8
            for (int j = 0; j < 32; ++j) {
                int m = w * 32 + j;
                if (m < NN && adj[n * NN + m] > 0) bits |= (1u << j);
            }
            packedT[w * NN + n] = bits;
        } else if (idx < PREP_ITEMS) {
            int i = idx - 11 * NN;
            int p = i >> 12, r = i & 4095;
            wab[i] = (half_t)(p ? W11[r] : W10[r]);
        }
        return;
    }

    __shared__ __attribute__((aligned(16))) half_t x16[64 * XS];
    __shared__ __attribute__((aligned(16))) half_t wbuf[2][64 * XS];
    const int row0 = bx * 64;

    const int lane = tid & 63, wv = tid >> 6;
    const int l15 = lane & 15, quad = lane >> 4;
    const int rbase = (wv & 3) * 16, ch = wv >> 2;
    const int qsh = quad * 4;

    // W9 B-fragments -> registers (16 x float4 from global; all 488 blocks
    // read the same 32 KB -> L2-hot; latency hides under the LDS staging).
    half4_t w9f[2][8];
    #pragma unroll
    for (int cc = 0; cc < 2; ++cc) {
        #pragma unroll
        for (int kk = 0; kk < 8; ++kk) {
            float4 f = *(const float4*)
                &W9[((ch * 2 + cc) * 16 + l15) * 128 + kk * 16 + qsh];
            half4_t hv;
            hv[0] = (half_t)f.x; hv[1] = (half_t)f.y;
            hv[2] = (half_t)f.z; hv[3] = (half_t)f.w;
            w9f[cc][kk] = hv;
        }
    }

    // stage x = concat(X, STE) -> f16
    #pragma unroll
    for (int idx = tid; idx < 2048; idx += 512) {
        int r = idx >> 5, c4 = idx & 31;
        int R = row0 + r;
        float4 f = {0.f, 0.f, 0.f, 0.f};
        if (R < NROWS)
            f = (c4 < 16) ? *(const float4*)(X + R * 64 + c4 * 4)
                          : *(const float4*)(STE + R * 64 + (c4 - 16) * 4);
        half4_t hv;
        hv[0] = (half_t)f.x; hv[1] = (half_t)f.y;
        hv[2] = (half_t)f.z; hv[3] = (half_t)f.w;
        *(half4_t*)&x16[r * XS + c4 * 4] = hv;
    }
    qkv_stage_wf(W7, wbuf[0], tid);
    qkv_stage_wf(W8, wbuf[1], tid);
    __syncthreads();    // the ONLY barrier in this kernel

    qkv_compute(x16, wbuf[0], b7, q, SCL, row0, rbase, ch, l15, quad);
    qkv_compute(x16, wbuf[1], b8, k, 1.0f, row0, rbase, ch, l15, quad);

    // phase 3 (v) from registers — no staging, no sync
    float4_t acc[2];
    #pragma unroll
    for (int cc = 0; cc < 2; ++cc) {
        float bias = b9[(ch * 2 + cc) * 16 + l15];
        acc[cc] = (float4_t){bias, bias, bias, bias};
    }
    #pragma unroll
    for (int kk = 0; kk < 8; ++kk) {
        half4_t a = *(const half4_t*)&x16[(rbase + l15) * XS + kk * 16 + qsh];
        #pragma unroll
        for (int cc = 0; cc < 2; ++cc)
            acc[cc] = __builtin_amdgcn_mfma_f32_16x16x16f16(
                a, w9f[cc][kk], acc[cc], 0, 0, 0);
    }
    #pragma unroll
    for (int cc = 0; cc < 2; ++cc) {
        #pragma unroll
        for (int rr = 0; rr < 4; ++rr) {
            int R = row0 + rbase + quad * 4 + rr;
            if (R < NROWS)
                v[R * 64 + (ch * 2 + cc) * 16 + l15] =
                    (half_t)gelu_f(acc[cc][rr]);
        }
    }
}

// ---------------------------------------------------------------------------
// Kernel 2: MFMA flash attention — round-4 two-pass version (best measured:
// VGPR 68 -> 3 blocks/CU x 8 waves; r5's register-cached single-pass cost
// +40 VGPR and lost a block of occupancy -> net regression. Reverted.)
// ---------------------------------------------------------------------------
__global__ __launch_bounds__(512) void attn_kernel(
    const half_t* __restrict__ q16g, const half_t* __restrict__ k16g,
    const half_t* __restrict__ v16g, const unsigned int* __restrict__ packedT,
    half_t* __restrict__ ao)
{
    __shared__ __attribute__((aligned(16))) half_t K16[336 * 20]; // [m][d0..15,pad]
    __shared__ __attribute__((aligned(16))) half_t VT16[16 * 344];// [c][m]
    const int tid = threadIdx.x;
    const int h = blockIdx.x, bt = blockIdx.y;
    const long base = (long)(bt * NN) * 64 + h * 8;

    const half4_t z4 = {(half_t)0.f, (half_t)0.f, (half_t)0.f, (half_t)0.f};

    // zero VT16, then ones row c=8
    for (int idx = tid; idx < 16 * 344 / 2; idx += 512)
        ((half2_t*)VT16)[idx] = (half2_t)(half_t)0.f;
    __syncthreads();
    for (int i = tid; i < 344; i += 512)
        VT16[8 * 344 + i] = (half_t)1.0f;

    // stage K rows (stride 20, d 8..15 zero)
    for (int r = tid; r < 336; r += 512) {
        half4_t ka = z4, kbv = z4;
        if (r < NN) {
            ka  = *(const half4_t*)(k16g + base + r * 64);
            kbv = *(const half4_t*)(k16g + base + r * 64 + 4);
        }
        *(half4_t*)&K16[r * 20]      = ka;
        *(half4_t*)&K16[r * 20 + 4]  = kbv;
        *(half4_t*)&K16[r * 20 + 8]  = z4;
        *(half4_t*)&K16[r * 20 + 12] = z4;
    }

    // stage V transposed via m-pair half2 writes (rows c = 0..7)
    for (int mp = tid; mp < 168; mp += 512) {
        int m0 = 2 * mp, m1 = 2 * mp + 1;
        half4_t v0a = z4, v0b = z4, v1a = z4, v1b = z4;
        if (m0 < NN) {
            v0a = *(const half4_t*)(v16g + base + m0 * 64);
            v0b = *(const half4_t*)(v16g + base + m0 * 64 + 4);
        }
        if (m1 < NN) {
            v1a = *(const half4_t*)(v16g + base + m1 * 64);
            v1b = *(const half4_t*)(v16g + base + m1 * 64 + 4);
        }
        #pragma unroll
        for (int c = 0; c < 4; ++c) {
            half2_t p0; p0[0] = v0a[c]; p0[1] = v1a[c];
            half2_t p1; p1[0] = v0b[c]; p1[1] = v1b[c];
            *(half2_t*)&VT16[c * 344 + 2 * mp]       = p0;
            *(half2_t*)&VT16[(c + 4) * 344 + 2 * mp] = p1;
        }
    }
    __syncthreads();

    const int lane = tid & 63;
    const int wv   = tid >> 6;     // 0..7
    const int l15  = lane & 15;
    const int quad = lane >> 4;
    const int qsh  = quad * 4;

    for (int t = wv; t < 21; t += 8) {
        const int n  = t * 16 + l15;
        const int nq = (n < NN) ? n : (NN - 1);   // clamp for global reads

        half4_t qf = z4;
        if (quad < 2)
            qf = *(const half4_t*)(q16g + base + (long)nq * 64 + qsh);

        // mask words hoisted: latency hides under pass A MFMAs
        unsigned int mb[11];
        #pragma unroll
        for (int w = 0; w < 11; ++w) mb[w] = packedT[w * NN + nq];

        // pass A: unmasked row max (>= all s; padded rows give s=0)
        float rm = 0.0f;
        #pragma unroll
        for (int mt = 0; mt < 21; ++mt) {
            half4_t kf = *(const half4_t*)&K16[(mt * 16 + l15) * 20 + qsh];
            float4_t sv = __builtin_amdgcn_mfma_f32_16x16x16f16(
                kf, qf, (float4_t){0.f, 0.f, 0.f, 0.f}, 0, 0, 0);
            rm = fmaxf(rm, fmaxf(fmaxf(sv[0], sv[1]), fmaxf(sv[2], sv[3])));
        }
        rm = fmaxf(rm, __shfl_xor(rm, 16, 64));
        rm = fmaxf(rm, __shfl_xor(rm, 32, 64));

        // pass B: s' = K.Q^T - rm (C-operand), p = exp2(s'), sum via ones-row
        const float4_t cinit = {-rm, -rm, -rm, -rm};
        float4_t acc = {0.f, 0.f, 0.f, 0.f};
        #pragma unroll
        for (int mt = 0; mt < 21; ++mt) {
            half4_t kf = *(const half4_t*)&K16[(mt * 16 + l15) * 20 + qsh];
            float4_t sv = __builtin_amdgcn_mfma_f32_16x16x16f16(
                kf, qf, cinit, 0, 0, 0);
            unsigned int sh = mb[mt >> 1] >> (((mt & 1) << 4) + qsh);
            float p0 = (sh & 1u) ? __builtin_amdgcn_exp2f(sv[0]) : 0.f;
            float p1 = (sh & 2u) ? __builtin_amdgcn_exp2f(sv[1]) : 0.f;
            float p2 = (sh & 4u) ? __builtin_amdgcn_exp2f(sv[2]) : 0.f;
            float p3 = (sh & 8u) ? __builtin_amdgcn_exp2f(sv[3]) : 0.f;
            half4_t pf;
            pf[0] = (half_t)p0; pf[1] = (half_t)p1;
            pf[2] = (half_t)p2; pf[3] = (half_t)p3;
            half4_t vf = *(const half4_t*)&VT16[l15 * 344 + mt * 16 + qsh];
            acc = __builtin_amdgcn_mfma_f32_16x16x16f16(vf, pf, acc, 0, 0, 0);
        }

        // sum for row n lives in lane (quad=2).acc[0]  (ones row c=8)
        float sum = __shfl(acc[0], 32 + l15, 64);

        if (quad < 2 && n < NN) {
            float inv = 1.0f / sum;
            half4_t o;
            o[0] = (half_t)(acc[0] * inv); o[1] = (half_t)(acc[1] * inv);
            o[2] = (half_t)(acc[2] * inv); o[3] = (half_t)(acc[3] * inv);
            *(half4_t*)(ao + base + (long)n * 64 + qsh) = o;
        }
    }
}

// ---------------------------------------------------------------------------
// Kernel 3: out = gelu(ao @ W10.T + b10) @ W11.T + b11 (verbatim baseline).
// ---------------------------------------------------------------------------
__global__ __launch_bounds__(512) void proj_kernel(
    const half_t* __restrict__ ao, const half_t* __restrict__ wab,
    const float* __restrict__ b10, const float* __restrict__ b11,
    float* __restrict__ out)
{
    __shared__ __attribute__((aligned(16))) half_t a16[64 * PS];
    __shared__ __attribute__((aligned(16))) half_t wA[64 * PS];
    __shared__ __attribute__((aligned(16))) half_t wB[64 * PS];
    __shared__ __attribute__((aligned(16))) half_t h16[64 * PS];
    const int tid  = threadIdx.x;
    const int row0 = blockIdx.x * 64;

    for (int idx = tid; idx < 512; idx += 512) {
        int r = idx >> 3, c8 = idx & 7;
        int R = row0 + r;
        uint4 u = {0u, 0u, 0u, 0u};
        if (R < NROWS) u = *(const uint4*)(ao + (long)R * 64 + c8 * 8);
        *(uint4*)&a16[r * PS + c8 * 8] = u;
        *(uint4*)&wA[r * PS + c8 * 8] = *(const uint4*)&wab[r * 64 + c8 * 8];
        *(uint4*)&wB[r * PS + c8 * 8] = *(const uint4*)&wab[4096 + r * 64 + c8 * 8];
    }
    __syncthreads();

    const int lane = tid & 63, wv = tid >> 6;
    const int l15 = lane & 15, quad = lane >> 4;
    const int rbase = (wv & 3) * 16, ch = wv >> 2;

    // stage 1: h = gelu(a @ W10.T + b10)
    float4_t acc[2];
    #pragma unroll
    for (int cc = 0; cc < 2; ++cc) {
        float bias = b10[(ch * 2 + cc) * 16 + l15];
        acc[cc] = (float4_t){bias, bias, bias, bias};
    }
    #pragma unroll
    for (int kk = 0; kk < 4; ++kk) {
        half4_t a = *(const half4_t*)&a16[(rbase + l15) * PS + kk * 16 + quad * 4];
        #pragma unroll
        for (int cc = 0; cc < 2; ++cc) {
            half4_t bf = *(const half4_t*)
                &wA[((ch * 2 + cc) * 16 + l15) * PS + kk * 16 + quad * 4];
            acc[cc] = __builtin_amdgcn_mfma_f32_16x16x16f16(a, bf, acc[cc], 0, 0, 0);
        }
    }
    #pragma unroll
    for (int cc = 0; cc < 2; ++cc) {
        #pragma unroll
        for (int rr = 0; rr < 4; ++rr)
            h16[(rbase + quad * 4 + rr) * PS + (ch * 2 + cc) * 16 + l15] =
                (half_t)gelu_f(acc[cc][rr]);
    }
    __syncthreads();

    // stage 2: out = h @ W11.T + b11
    #pragma unroll
    for (int cc = 0; cc < 2; ++cc) {
        float bias = b11[(ch * 2 + cc) * 16 + l15];
        acc[cc] = (float4_t){bias, bias, bias, bias};
    }
    #pragma unroll
    for (int kk = 0; kk < 4; ++kk) {
        half4_t a = *(const half4_t*)&h16[(rbase + l15) * PS + kk * 16 + quad * 4];
        #pragma unroll
        for (int cc = 0; cc < 2; ++cc) {
            half4_t bf = *(const half4_t*)
                &wB[((ch * 2 + cc) * 16 + l15) * PS + kk * 16 + quad * 4];
            acc[cc] = __builtin_amdgcn_mfma_f32_16x16x16f16(a, bf, acc[cc], 0, 0, 0);
        }
    }
    #pragma unroll
    for (int cc = 0; cc < 2; ++cc) {
        #pragma unroll
        for (int rr = 0; rr < 4; ++rr) {
            int R = row0 + rbase + quad * 4 + rr;
            if (R < NROWS)
                out[R * 64 + (ch * 2 + cc) * 16 + l15] = acc[cc][rr];
        }
    }
}

extern "C" void kernel_launch(void* const* d_in, const int* in_sizes, int n_in,
                              void* d_out, int out_size, void* d_ws, size_t ws_size,
                              hipStream_t stream) {
    const float* X   = (const float*)d_in[0];
    const float* STE = (const float*)d_in[1];
    const int*   adj = (const int*)d_in[2];
    const float* W7  = (const float*)d_in[3];
    const float* b7  = (const float*)d_in[4];
    const float* W8  = (const float*)d_in[5];
    const float* b8  = (const float*)d_in[6];
    const float* W9  = (const float*)d_in[7];
    const float* b9  = (const float*)d_in[8];
    const float* W10 = (const float*)d_in[9];
    const float* b10 = (const float*)d_in[10];
    const float* W11 = (const float*)d_in[11];
    const float* b11 = (const float*)d_in[12];

    char* wsb = (char*)d_ws;
    const long S = (long)NROWS * 64;           // 1,996,800 elements
    half_t* qb = (half_t*)wsb;
    half_t* kb = qb + S;
    half_t* vb = qb + 2 * S;
    half_t* ab = qb + 3 * S;
    unsigned int* pk = (unsigned int*)(wsb + 4 * S * sizeof(half_t));
    half_t* wab = (half_t*)(wsb + 4 * S * sizeof(half_t) + 16384);

    qkv_kernel<<<dim3(TOT_BLKS), 512, 0, stream>>>(
        X, STE, adj, W7, b7, W8, b8, W9, b9, W10, W11,
        qb, kb, vb, pk, wab);
    attn_kernel<<<dim3(8, BT), 512, 0, stream>>>(qb, kb, vb, pk, ab);
    proj_kernel<<<dim3((NROWS + 63) / 64), 512, 0, stream>>>(
        ab, wab, b10, b11, (float*)d_out);
}

// Round 7
// 144.847 us; speedup vs baseline: 1.0556x; 1.0216x over previous
//
#include <hip/hip_runtime.h>
#include <math.h>

#define NN 325
#define BT 96
#define NROWS (BT * NN)   // 31200
// fold softmax scale and log2(e) into q: exp(s/sqrt8) == exp2(s * SCL)
#define SCL (0.35355339059327373f * 1.4426950408889634f)
#define QKV_BLKS ((NROWS + 63) / 64)        // 488
#define PREP_ITEMS (11 * NN + 8192)         // 3575 masks + 8192 wab = 11767
#define PREP_BLKS ((PREP_ITEMS + 511) / 512) // 23
#define TOT_BLKS (QKV_BLKS + PREP_BLKS)     // 511

typedef _Float16 half_t;
typedef half_t half8_t __attribute__((ext_vector_type(8)));
typedef half_t half4_t __attribute__((ext_vector_type(4)));
typedef half_t half2_t __attribute__((ext_vector_type(2)));
typedef float float4_t __attribute__((ext_vector_type(4)));

__device__ __forceinline__ float gelu_f(float x) {
    return 0.5f * x * (1.0f + erff(x * 0.70710678118654752f));
}

#define XS 136   // half stride per 128-k row (qkv)
#define PS 72    // half stride per 64-k row (proj)

// Stage a 64x128 f32 weight matrix into LDS as f16.
__device__ __forceinline__ void qkv_stage_wf(const float* __restrict__ src,
                                             half_t* dst, int tid)
{
    #pragma unroll
    for (int idx = tid; idx < 1024; idx += 512) {
        int c = idx >> 4, g = idx & 15;
        const float4* s4 = (const float4*)&src[c * 128 + g * 8];
        float4 a = s4[0], b = s4[1];
        half8_t h;
        h[0] = (half_t)a.x; h[1] = (half_t)a.y;
        h[2] = (half_t)a.z; h[3] = (half_t)a.w;
        h[4] = (half_t)b.x; h[5] = (half_t)b.y;
        h[6] = (half_t)b.z; h[7] = (half_t)b.w;
        *(half8_t*)&dst[c * XS + g * 8] = h;
    }
}

__device__ __forceinline__ void qkv_compute(
    const half_t* x16, const half_t* wb, const float* __restrict__ b,
    half_t* __restrict__ outp, float oscale,
    int row0, int rbase, int ch, int l15, int quad)
{
    float4_t acc[2];
    #pragma unroll
    for (int cc = 0; cc < 2; ++cc) {
        float bias = b[(ch * 2 + cc) * 16 + l15];
        acc[cc] = (float4_t){bias, bias, bias, bias};
    }
    #pragma unroll
    for (int kk = 0; kk < 8; ++kk) {
        half4_t a = *(const half4_t*)&x16[(rbase + l15) * XS + kk * 16 + quad * 4];
        #pragma unroll
        for (int cc = 0; cc < 2; ++cc) {
            half4_t bf = *(const half4_t*)
                &wb[((ch * 2 + cc) * 16 + l15) * XS + kk * 16 + quad * 4];
            acc[cc] = __builtin_amdgcn_mfma_f32_16x16x16f16(a, bf, acc[cc], 0, 0, 0);
        }
    }
    #pragma unroll
    for (int cc = 0; cc < 2; ++cc) {
        #pragma unroll
        for (int rr = 0; rr < 4; ++rr) {
            int R = row0 + rbase + quad * 4 + rr;
            if (R < NROWS)
                outp[R * 64 + (ch * 2 + cc) * 16 + l15] =
                    (half_t)(gelu_f(acc[cc][rr]) * oscale);
        }
    }
}

// ---------------------------------------------------------------------------
// Kernel 1: q/k/v = gelu(concat(X,STE) @ W.T + b) via f16 MFMA.
// r4 ping-pong structure (best measured): staging of W(p+1) overlaps compute
// of phase p. (r6 lesson: the single-sync variant serialized staging and
// regressed — overlap, not barrier count, is what matters at 2 blocks/CU.)
// Blocks [488,511): prep work (adj bitmasks + wab f16) for later launches.
// ---------------------------------------------------------------------------
__global__ __launch_bounds__(512) void qkv_kernel(
    const float* __restrict__ X, const float* __restrict__ STE,
    const int* __restrict__ adj,
    const float* __restrict__ W7, const float* __restrict__ b7,
    const float* __restrict__ W8, const float* __restrict__ b8,
    const float* __restrict__ W9, const float* __restrict__ b9,
    const float* __restrict__ W10, const float* __restrict__ W11,
    half_t* __restrict__ q, half_t* __restrict__ k, half_t* __restrict__ v,
    unsigned int* __restrict__ packedT, half_t* __restrict__ wab)
{
    const int tid = threadIdx.x;
    const int bx  = blockIdx.x;

    if (bx >= QKV_BLKS) {
        // ------- prep tail blocks: masks + W10/W11 f16 conversion ---------
        int idx = (bx - QKV_BLKS) * 512 + tid;
        if (idx < 11 * NN) {
            int w = idx / NN, n = idx - w * NN;
            unsigned int bits = 0u;
            #pragma unroll 8
            for (int j = 0; j < 32; ++j) {
                int m = w * 32 + j;
                if (m < NN && adj[n * NN + m] > 0) bits |= (1u << j);
            }
            packedT[w * NN + n] = bits;
        } else if (idx < PREP_ITEMS) {
            int i = idx - 11 * NN;
            int p = i >> 12, r = i & 4095;
            wab[i] = (half_t)(p ? W11[r] : W10[r]);
        }
        return;
    }

    __shared__ __attribute__((aligned(16))) half_t x16[64 * XS];
    __shared__ __attribute__((aligned(16))) half_t wbuf[2][64 * XS];
    const int row0 = bx * 64;

    // stage x = concat(X, STE) -> f16
    #pragma unroll
    for (int idx = tid; idx < 2048; idx += 512) {
        int r = idx >> 5, c4 = idx & 31;
        int R = row0 + r;
        float4 f = {0.f, 0.f, 0.f, 0.f};
        if (R < NROWS)
            f = (c4 < 16) ? *(const float4*)(X + R * 64 + c4 * 4)
                          : *(const float4*)(STE + R * 64 + (c4 - 16) * 4);
        half4_t hv;
        hv[0] = (half_t)f.x; hv[1] = (half_t)f.y;
        hv[2] = (half_t)f.z; hv[3] = (half_t)f.w;
        *(half4_t*)&x16[r * XS + c4 * 4] = hv;
    }
    qkv_stage_wf(W7, wbuf[0], tid);          // W7 (f32 -> f16 inline)
    __syncthreads();

    const int lane = tid & 63, wv = tid >> 6;
    const int l15 = lane & 15, quad = lane >> 4;
    const int rbase = (wv & 3) * 16, ch = wv >> 2;

    qkv_stage_wf(W8, wbuf[1], tid);          // W8 (overlaps phase 0)
    qkv_compute(x16, wbuf[0], b7, q, SCL, row0, rbase, ch, l15, quad);
    __syncthreads();

    qkv_stage_wf(W9, wbuf[0], tid);          // W9 (overlaps phase 1)
    qkv_compute(x16, wbuf[1], b8, k, 1.0f, row0, rbase, ch, l15, quad);
    __syncthreads();

    qkv_compute(x16, wbuf[0], b9, v, 1.0f, row0, rbase, ch, l15, quad);
}

// ---------------------------------------------------------------------------
// Kernel 2: MFMA flash attention, SINGLE-PASS via norm bound.
// rm need not be the true row max — any upper bound keeps exp2 <= 1-ish and
// cancels under normalization. Cauchy-Schwarz: s = q.k <= |q_n| * max_m|k_m|.
//  - max_m|k_m|^2: folded into K staging + wave-max + 8-word LDS exchange
//    (reuses the existing barrier).
//  - |q_n|^2: 4 FMAs on qf + 2 shfl_xor adds (quads 2/3 contribute 0).
// Deletes pass A entirely (21 serial MFMA+fmax per tile, 21 K16 LDS sweeps)
// at ZERO extra VGPR (r5 lesson: occupancy is the binding constraint).
// Looseness d => p = exp2(s-rm) scaled by 2^-d; f16 is floating point, so
// relative precision is unchanged until p_max < 2^-14 (huge headroom: d~1-3).
// ---------------------------------------------------------------------------
__global__ __launch_bounds__(512) void attn_kernel(
    const half_t* __restrict__ q16g, const half_t* __restrict__ k16g,
    const half_t* __restrict__ v16g, const unsigned int* __restrict__ packedT,
    half_t* __restrict__ ao)
{
    __shared__ __attribute__((aligned(16))) half_t K16[336 * 20]; // [m][d0..15,pad]
    __shared__ __attribute__((aligned(16))) half_t VT16[16 * 344];// [c][m]
    __shared__ float smax8[8];
    const int tid = threadIdx.x;
    const int h = blockIdx.x, bt = blockIdx.y;
    const long base = (long)(bt * NN) * 64 + h * 8;

    const half4_t z4 = {(half_t)0.f, (half_t)0.f, (half_t)0.f, (half_t)0.f};

    // zero VT16, then ones row c=8
    for (int idx = tid; idx < 16 * 344 / 2; idx += 512)
        ((half2_t*)VT16)[idx] = (half2_t)(half_t)0.f;
    __syncthreads();
    for (int i = tid; i < 344; i += 512)
        VT16[8 * 344 + i] = (half_t)1.0f;

    // stage K rows (stride 20, d 8..15 zero) + per-row |k|^2
    float nk2 = 0.0f;
    for (int r = tid; r < 336; r += 512) {
        half4_t ka = z4, kbv = z4;
        if (r < NN) {
            ka  = *(const half4_t*)(k16g + base + r * 64);
            kbv = *(const half4_t*)(k16g + base + r * 64 + 4);
        }
        *(half4_t*)&K16[r * 20]      = ka;
        *(half4_t*)&K16[r * 20 + 4]  = kbv;
        *(half4_t*)&K16[r * 20 + 8]  = z4;
        *(half4_t*)&K16[r * 20 + 12] = z4;
        #pragma unroll
        for (int j = 0; j < 4; ++j) {
            float fa = (float)ka[j], fb = (float)kbv[j];
            nk2 = fmaf(fa, fa, nk2);
            nk2 = fmaf(fb, fb, nk2);
        }
    }

    // stage V transposed via m-pair half2 writes (rows c = 0..7)
    for (int mp = tid; mp < 168; mp += 512) {
        int m0 = 2 * mp, m1 = 2 * mp + 1;
        half4_t v0a = z4, v0b = z4, v1a = z4, v1b = z4;
        if (m0 < NN) {
            v0a = *(const half4_t*)(v16g + base + m0 * 64);
            v0b = *(const half4_t*)(v16g + base + m0 * 64 + 4);
        }
        if (m1 < NN) {
            v1a = *(const half4_t*)(v16g + base + m1 * 64);
            v1b = *(const half4_t*)(v16g + base + m1 * 64 + 4);
        }
        #pragma unroll
        for (int c = 0; c < 4; ++c) {
            half2_t p0; p0[0] = v0a[c]; p0[1] = v1a[c];
            half2_t p1; p1[0] = v0b[c]; p1[1] = v1b[c];
            *(half2_t*)&VT16[c * 344 + 2 * mp]       = p0;
            *(half2_t*)&VT16[(c + 4) * 344 + 2 * mp] = p1;
        }
    }

    // block max of |k|^2 (wave butterfly + 8-word LDS, reusing the barrier)
    #pragma unroll
    for (int off = 32; off >= 1; off >>= 1)
        nk2 = fmaxf(nk2, __shfl_xor(nk2, off, 64));
    if ((tid & 63) == 0) smax8[tid >> 6] = nk2;
    __syncthreads();

    const float maxk2 = fmaxf(
        fmaxf(fmaxf(smax8[0], smax8[1]), fmaxf(smax8[2], smax8[3])),
        fmaxf(fmaxf(smax8[4], smax8[5]), fmaxf(smax8[6], smax8[7])));

    const int lane = tid & 63;
    const int wv   = tid >> 6;     // 0..7
    const int l15  = lane & 15;
    const int quad = lane >> 4;
    const int qsh  = quad * 4;

    for (int t = wv; t < 21; t += 8) {
        const int n  = t * 16 + l15;
        const int nq = (n < NN) ? n : (NN - 1);   // clamp for global reads

        half4_t qf = z4;
        if (quad < 2)
            qf = *(const half4_t*)(q16g + base + (long)nq * 64 + qsh);

        // rm = |q_n| * max_m|k_m|  (upper bound on all scores for row n)
        float ssq = 0.0f;
        #pragma unroll
        for (int j = 0; j < 4; ++j) {
            float fq = (float)qf[j];
            ssq = fmaf(fq, fq, ssq);
        }
        ssq += __shfl_xor(ssq, 16, 64);
        ssq += __shfl_xor(ssq, 32, 64);
        const float rm = sqrtf(ssq * maxk2);

        // mask words: latency hides under the score MFMAs
        unsigned int mb[11];
        #pragma unroll
        for (int w = 0; w < 11; ++w) mb[w] = packedT[w * NN + nq];

        // single pass: s' = K.Q^T - rm (C-operand), p = exp2(s'), ones-row sum
        const float4_t cinit = {-rm, -rm, -rm, -rm};
        float4_t acc = {0.f, 0.f, 0.f, 0.f};
        #pragma unroll
        for (int mt = 0; mt < 21; ++mt) {
            half4_t kf = *(const half4_t*)&K16[(mt * 16 + l15) * 20 + qsh];
            float4_t sv = __builtin_amdgcn_mfma_f32_16x16x16f16(
                kf, qf, cinit, 0, 0, 0);
            unsigned int sh = mb[mt >> 1] >> (((mt & 1) << 4) + qsh);
            float p0 = (sh & 1u) ? __builtin_amdgcn_exp2f(sv[0]) : 0.f;
            float p1 = (sh & 2u) ? __builtin_amdgcn_exp2f(sv[1]) : 0.f;
            float p2 = (sh & 4u) ? __builtin_amdgcn_exp2f(sv[2]) : 0.f;
            float p3 = (sh & 8u) ? __builtin_amdgcn_exp2f(sv[3]) : 0.f;
            half4_t pf;
            pf[0] = (half_t)p0; pf[1] = (half_t)p1;
            pf[2] = (half_t)p2; pf[3] = (half_t)p3;
            half4_t vf = *(const half4_t*)&VT16[l15 * 344 + mt * 16 + qsh];
            acc = __builtin_amdgcn_mfma_f32_16x16x16f16(vf, pf, acc, 0, 0, 0);
        }

        // sum for row n lives in lane (quad=2).acc[0]  (ones row c=8)
        float sum = __shfl(acc[0], 32 + l15, 64);

        if (quad < 2 && n < NN) {
            float inv = 1.0f / sum;
            half4_t o;
            o[0] = (half_t)(acc[0] * inv); o[1] = (half_t)(acc[1] * inv);
            o[2] = (half_t)(acc[2] * inv); o[3] = (half_t)(acc[3] * inv);
            *(half4_t*)(ao + base + (long)n * 64 + qsh) = o;
        }
    }
}

// ---------------------------------------------------------------------------
// Kernel 3: out = gelu(ao @ W10.T + b10) @ W11.T + b11 (verbatim baseline).
// ---------------------------------------------------------------------------
__global__ __launch_bounds__(512) void proj_kernel(
    const half_t* __restrict__ ao, const half_t* __restrict__ wab,
    const float* __restrict__ b10, const float* __restrict__ b11,
    float* __restrict__ out)
{
    __shared__ __attribute__((aligned(16))) half_t a16[64 * PS];
    __shared__ __attribute__((aligned(16))) half_t wA[64 * PS];
    __shared__ __attribute__((aligned(16))) half_t wB[64 * PS];
    __shared__ __attribute__((aligned(16))) half_t h16[64 * PS];
    const int tid  = threadIdx.x;
    const int row0 = blockIdx.x * 64;

    for (int idx = tid; idx < 512; idx += 512) {
        int r = idx >> 3, c8 = idx & 7;
        int R = row0 + r;
        uint4 u = {0u, 0u, 0u, 0u};
        if (R < NROWS) u = *(const uint4*)(ao + (long)R * 64 + c8 * 8);
        *(uint4*)&a16[r * PS + c8 * 8] = u;
        *(uint4*)&wA[r * PS + c8 * 8] = *(const uint4*)&wab[r * 64 + c8 * 8];
        *(uint4*)&wB[r * PS + c8 * 8] = *(const uint4*)&wab[4096 + r * 64 + c8 * 8];
    }
    __syncthreads();

    const int lane = tid & 63, wv = tid >> 6;
    const int l15 = lane & 15, quad = lane >> 4;
    const int rbase = (wv & 3) * 16, ch = wv >> 2;

    // stage 1: h = gelu(a @ W10.T + b10)
    float4_t acc[2];
    #pragma unroll
    for (int cc = 0; cc < 2; ++cc) {
        float bias = b10[(ch * 2 + cc) * 16 + l15];
        acc[cc] = (float4_t){bias, bias, bias, bias};
    }
    #pragma unroll
    for (int kk = 0; kk < 4; ++kk) {
        half4_t a = *(const half4_t*)&a16[(rbase + l15) * PS + kk * 16 + quad * 4];
        #pragma unroll
        for (int cc = 0; cc < 2; ++cc) {
            half4_t bf = *(const half4_t*)
                &wA[((ch * 2 + cc) * 16 + l15) * PS + kk * 16 + quad * 4];
            acc[cc] = __builtin_amdgcn_mfma_f32_16x16x16f16(a, bf, acc[cc], 0, 0, 0);
        }
    }
    #pragma unroll
    for (int cc = 0; cc < 2; ++cc) {
        #pragma unroll
        for (int rr = 0; rr < 4; ++rr)
            h16[(rbase + quad * 4 + rr) * PS + (ch * 2 + cc) * 16 + l15] =
                (half_t)gelu_f(acc[cc][rr]);
    }
    __syncthreads();

    // stage 2: out = h @ W11.T + b11
    #pragma unroll
    for (int cc = 0; cc < 2; ++cc) {
        float bias = b11[(ch * 2 + cc) * 16 + l15];
        acc[cc] = (float4_t){bias, bias, bias, bias};
    }
    #pragma unroll
    for (int kk = 0; kk < 4; ++kk) {
        half4_t a = *(const half4_t*)&h16[(rbase + l15) * PS + kk * 16 + quad * 4];
        #pragma unroll
        for (int cc = 0; cc < 2; ++cc) {
            half4_t bf = *(const half4_t*)
                &wB[((ch * 2 + cc) * 16 + l15) * PS + kk * 16 + quad * 4];
            acc[cc] = __builtin_amdgcn_mfma_f32_16x16x16f16(a, bf, acc[cc], 0, 0, 0);
        }
    }
    #pragma unroll
    for (int cc = 0; cc < 2; ++cc) {
        #pragma unroll
        for (int rr = 0; rr < 4; ++rr) {
            int R = row0 + rbase + quad * 4 + rr;
            if (R < NROWS)
                out[R * 64 + (ch * 2 + cc) * 16 + l15] = acc[cc][rr];
        }
    }
}

extern "C" void kernel_launch(void* const* d_in, const int* in_sizes, int n_in,
                              void* d_out, int out_size, void* d_ws, size_t ws_size,
                              hipStream_t stream) {
    const float* X   = (const float*)d_in[0];
    const float* STE = (const float*)d_in[1];
    const int*   adj = (const int*)d_in[2];
    const float* W7  = (const float*)d_in[3];
    const float* b7  = (const float*)d_in[4];
    const float* W8  = (const float*)d_in[5];
    const float* b8  = (const float*)d_in[6];
    const float* W9  = (const float*)d_in[7];
    const float* b9  = (const float*)d_in[8];
    const float* W10 = (const float*)d_in[9];
    const float* b10 = (const float*)d_in[10];
    const float* W11 = (const float*)d_in[11];
    const float* b11 = (const float*)d_in[12];

    char* wsb = (char*)d_ws;
    const long S = (long)NROWS * 64;           // 1,996,800 elements
    half_t* qb = (half_t*)wsb;
    half_t* kb = qb + S;
    half_t* vb = qb + 2 * S;
    half_t* ab = qb + 3 * S;
    unsigned int* pk = (unsigned int*)(wsb + 4 * S * sizeof(half_t));
    half_t* wab = (half_t*)(wsb + 4 * S * sizeof(half_t) + 16384);

    qkv_kernel<<<dim3(TOT_BLKS), 512, 0, stream>>>(
        X, STE, adj, W7, b7, W8, b8, W9, b9, W10, W11,
        qb, kb, vb, pk, wab);
    attn_kernel<<<dim3(8, BT), 512, 0, stream>>>(qb, kb, vb, pk, ab);
    proj_kernel<<<dim3((NROWS + 63) / 64), 512, 0, stream>>>(
        ab, wab, b10, b11, (float*)d_out);
}

// Round 8
// 138.637 us; speedup vs baseline: 1.1029x; 1.0448x over previous
//
#include <hip/hip_runtime.h>
#include <math.h>

#define NN 325
#define BT 96
#define NROWS (BT * NN)   // 31200
// fold softmax scale and log2(e) into q: exp(s/sqrt8) == exp2(s * SCL)
#define SCL (0.35355339059327373f * 1.4426950408889634f)
#define QKV_BLKS ((NROWS + 63) / 64)        // 488
#define PREP_ITEMS (11 * NN + 8192)         // 3575 masks + 8192 wab = 11767
#define PREP_BLKS ((PREP_ITEMS + 511) / 512) // 23
#define TOT_BLKS (QKV_BLKS + PREP_BLKS)     // 511

typedef _Float16 half_t;
typedef half_t half8_t __attribute__((ext_vector_type(8)));
typedef half_t half4_t __attribute__((ext_vector_type(4)));
typedef half_t half2_t __attribute__((ext_vector_type(2)));
typedef float float4_t __attribute__((ext_vector_type(4)));

__device__ __forceinline__ float gelu_f(float x) {
    return 0.5f * x * (1.0f + erff(x * 0.70710678118654752f));
}

#define XS 136   // half stride per 128-k row (qkv)
#define PS 72    // half stride per 64-k row (proj)

// Stage a 64x128 f32 weight matrix into LDS as f16.
__device__ __forceinline__ void qkv_stage_wf(const float* __restrict__ src,
                                             half_t* dst, int tid)
{
    #pragma unroll
    for (int idx = tid; idx < 1024; idx += 512) {
        int c = idx >> 4, g = idx & 15;
        const float4* s4 = (const float4*)&src[c * 128 + g * 8];
        float4 a = s4[0], b = s4[1];
        half8_t h;
        h[0] = (half_t)a.x; h[1] = (half_t)a.y;
        h[2] = (half_t)a.z; h[3] = (half_t)a.w;
        h[4] = (half_t)b.x; h[5] = (half_t)b.y;
        h[6] = (half_t)b.z; h[7] = (half_t)b.w;
        *(half8_t*)&dst[c * XS + g * 8] = h;
    }
}

__device__ __forceinline__ void qkv_compute(
    const half_t* x16, const half_t* wb, const float* __restrict__ b,
    half_t* __restrict__ outp, float oscale,
    int row0, int rbase, int ch, int l15, int quad)
{
    float4_t acc[2];
    #pragma unroll
    for (int cc = 0; cc < 2; ++cc) {
        float bias = b[(ch * 2 + cc) * 16 + l15];
        acc[cc] = (float4_t){bias, bias, bias, bias};
    }
    #pragma unroll
    for (int kk = 0; kk < 8; ++kk) {
        half4_t a = *(const half4_t*)&x16[(rbase + l15) * XS + kk * 16 + quad * 4];
        #pragma unroll
        for (int cc = 0; cc < 2; ++cc) {
            half4_t bf = *(const half4_t*)
                &wb[((ch * 2 + cc) * 16 + l15) * XS + kk * 16 + quad * 4];
            acc[cc] = __builtin_amdgcn_mfma_f32_16x16x16f16(a, bf, acc[cc], 0, 0, 0);
        }
    }
    #pragma unroll
    for (int cc = 0; cc < 2; ++cc) {
        #pragma unroll
        for (int rr = 0; rr < 4; ++rr) {
            int R = row0 + rbase + quad * 4 + rr;
            if (R < NROWS)
                outp[R * 64 + (ch * 2 + cc) * 16 + l15] =
                    (half_t)(gelu_f(acc[cc][rr]) * oscale);
        }
    }
}

// ---------------------------------------------------------------------------
// Kernel 1: q/k/v = gelu(concat(X,STE) @ W.T + b) via f16 MFMA.
// r4 ping-pong structure (best measured). Blocks [488,511): prep work.
// ---------------------------------------------------------------------------
__global__ __launch_bounds__(512) void qkv_kernel(
    const float* __restrict__ X, const float* __restrict__ STE,
    const int* __restrict__ adj,
    const float* __restrict__ W7, const float* __restrict__ b7,
    const float* __restrict__ W8, const float* __restrict__ b8,
    const float* __restrict__ W9, const float* __restrict__ b9,
    const float* __restrict__ W10, const float* __restrict__ W11,
    half_t* __restrict__ q, half_t* __restrict__ k, half_t* __restrict__ v,
    unsigned int* __restrict__ packedT, half_t* __restrict__ wab)
{
    const int tid = threadIdx.x;
    const int bx  = blockIdx.x;

    if (bx >= QKV_BLKS) {
        // ------- prep tail blocks: masks + W10/W11 f16 conversion ---------
        int idx = (bx - QKV_BLKS) * 512 + tid;
        if (idx < 11 * NN) {
            int w = idx / NN, n = idx - w * NN;
            unsigned int bits = 0u;
            #pragma unroll 8
            for (int j = 0; j < 32; ++j) {
                int m = w * 32 + j;
                if (m < NN && adj[n * NN + m] > 0) bits |= (1u << j);
            }
            packedT[w * NN + n] = bits;
        } else if (idx < PREP_ITEMS) {
            int i = idx - 11 * NN;
            int p = i >> 12, r = i & 4095;
            wab[i] = (half_t)(p ? W11[r] : W10[r]);
        }
        return;
    }

    __shared__ __attribute__((aligned(16))) half_t x16[64 * XS];
    __shared__ __attribute__((aligned(16))) half_t wbuf[2][64 * XS];
    const int row0 = bx * 64;

    // stage x = concat(X, STE) -> f16
    #pragma unroll
    for (int idx = tid; idx < 2048; idx += 512) {
        int r = idx >> 5, c4 = idx & 31;
        int R = row0 + r;
        float4 f = {0.f, 0.f, 0.f, 0.f};
        if (R < NROWS)
            f = (c4 < 16) ? *(const float4*)(X + R * 64 + c4 * 4)
                          : *(const float4*)(STE + R * 64 + (c4 - 16) * 4);
        half4_t hv;
        hv[0] = (half_t)f.x; hv[1] = (half_t)f.y;
        hv[2] = (half_t)f.z; hv[3] = (half_t)f.w;
        *(half4_t*)&x16[r * XS + c4 * 4] = hv;
    }
    qkv_stage_wf(W7, wbuf[0], tid);          // W7 (f32 -> f16 inline)
    __syncthreads();

    const int lane = tid & 63, wv = tid >> 6;
    const int l15 = lane & 15, quad = lane >> 4;
    const int rbase = (wv & 3) * 16, ch = wv >> 2;

    qkv_stage_wf(W8, wbuf[1], tid);          // W8 (overlaps phase 0)
    qkv_compute(x16, wbuf[0], b7, q, SCL, row0, rbase, ch, l15, quad);
    __syncthreads();

    qkv_stage_wf(W9, wbuf[0], tid);          // W9 (overlaps phase 1)
    qkv_compute(x16, wbuf[1], b8, k, 1.0f, row0, rbase, ch, l15, quad);
    __syncthreads();

    qkv_compute(x16, wbuf[0], b9, v, 1.0f, row0, rbase, ch, l15, quad);
}

// ---------------------------------------------------------------------------
// Kernel 2: MFMA flash attention, single-pass norm-bound (r7) + XCD-locality
// swizzle (NEW): 1-D grid with h = bx/BT, bt = bx%BT. Since 96 % 8 == 0,
// linear id % 8 == bt % 8 -> all 8 head-blocks of a bt land on the SAME XCD,
// so the q/k/v/mask lines they share (64B lines span 4 heads) are fetched
// from HBM once per XCD instead of 8 times. (r7 lesson: attn is bound by
// its 47MB fetch = 4x overfetch from cross-XCD L2 misses, not by compute.)
// ---------------------------------------------------------------------------
__global__ __launch_bounds__(512) void attn_kernel(
    const half_t* __restrict__ q16g, const half_t* __restrict__ k16g,
    const half_t* __restrict__ v16g, const unsigned int* __restrict__ packedT,
    half_t* __restrict__ ao)
{
    __shared__ __attribute__((aligned(16))) half_t K16[336 * 20]; // [m][d0..15,pad]
    __shared__ __attribute__((aligned(16))) half_t VT16[16 * 344];// [c][m]
    __shared__ float smax8[8];
    const int tid = threadIdx.x;
    const int bx  = blockIdx.x;
    const int h   = bx / BT;          // 0..7
    const int bt  = bx - h * BT;      // 0..95 ; id%8 == bt%8 -> same XCD
    const long base = (long)(bt * NN) * 64 + h * 8;

    const half4_t z4 = {(half_t)0.f, (half_t)0.f, (half_t)0.f, (half_t)0.f};

    // zero VT16, then ones row c=8
    for (int idx = tid; idx < 16 * 344 / 2; idx += 512)
        ((half2_t*)VT16)[idx] = (half2_t)(half_t)0.f;
    __syncthreads();
    for (int i = tid; i < 344; i += 512)
        VT16[8 * 344 + i] = (half_t)1.0f;

    // stage K rows (stride 20, d 8..15 zero) + per-row |k|^2
    float nk2 = 0.0f;
    for (int r = tid; r < 336; r += 512) {
        half4_t ka = z4, kbv = z4;
        if (r < NN) {
            ka  = *(const half4_t*)(k16g + base + r * 64);
            kbv = *(const half4_t*)(k16g + base + r * 64 + 4);
        }
        *(half4_t*)&K16[r * 20]      = ka;
        *(half4_t*)&K16[r * 20 + 4]  = kbv;
        *(half4_t*)&K16[r * 20 + 8]  = z4;
        *(half4_t*)&K16[r * 20 + 12] = z4;
        #pragma unroll
        for (int j = 0; j < 4; ++j) {
            float fa = (float)ka[j], fb = (float)kbv[j];
            nk2 = fmaf(fa, fa, nk2);
            nk2 = fmaf(fb, fb, nk2);
        }
    }

    // stage V transposed via m-pair half2 writes (rows c = 0..7)
    for (int mp = tid; mp < 168; mp += 512) {
        int m0 = 2 * mp, m1 = 2 * mp + 1;
        half4_t v0a = z4, v0b = z4, v1a = z4, v1b = z4;
        if (m0 < NN) {
            v0a = *(const half4_t*)(v16g + base + m0 * 64);
            v0b = *(const half4_t*)(v16g + base + m0 * 64 + 4);
        }
        if (m1 < NN) {
            v1a = *(const half4_t*)(v16g + base + m1 * 64);
            v1b = *(const half4_t*)(v16g + base + m1 * 64 + 4);
        }
        #pragma unroll
        for (int c = 0; c < 4; ++c) {
            half2_t p0; p0[0] = v0a[c]; p0[1] = v1a[c];
            half2_t p1; p1[0] = v0b[c]; p1[1] = v1b[c];
            *(half2_t*)&VT16[c * 344 + 2 * mp]       = p0;
            *(half2_t*)&VT16[(c + 4) * 344 + 2 * mp] = p1;
        }
    }

    // block max of |k|^2 (wave butterfly + 8-word LDS, reusing the barrier)
    #pragma unroll
    for (int off = 32; off >= 1; off >>= 1)
        nk2 = fmaxf(nk2, __shfl_xor(nk2, off, 64));
    if ((tid & 63) == 0) smax8[tid >> 6] = nk2;
    __syncthreads();

    const float maxk2 = fmaxf(
        fmaxf(fmaxf(smax8[0], smax8[1]), fmaxf(smax8[2], smax8[3])),
        fmaxf(fmaxf(smax8[4], smax8[5]), fmaxf(smax8[6], smax8[7])));

    const int lane = tid & 63;
    const int wv   = tid >> 6;     // 0..7
    const int l15  = lane & 15;
    const int quad = lane >> 4;
    const int qsh  = quad * 4;

    for (int t = wv; t < 21; t += 8) {
        const int n  = t * 16 + l15;
        const int nq = (n < NN) ? n : (NN - 1);   // clamp for global reads

        half4_t qf = z4;
        if (quad < 2)
            qf = *(const half4_t*)(q16g + base + (long)nq * 64 + qsh);

        // rm = |q_n| * max_m|k_m|  (upper bound on all scores for row n)
        float ssq = 0.0f;
        #pragma unroll
        for (int j = 0; j < 4; ++j) {
            float fq = (float)qf[j];
            ssq = fmaf(fq, fq, ssq);
        }
        ssq += __shfl_xor(ssq, 16, 64);
        ssq += __shfl_xor(ssq, 32, 64);
        const float rm = sqrtf(ssq * maxk2);

        // mask words: latency hides under the score MFMAs
        unsigned int mb[11];
        #pragma unroll
        for (int w = 0; w < 11; ++w) mb[w] = packedT[w * NN + nq];

        // single pass: s' = K.Q^T - rm (C-operand), p = exp2(s'), ones-row sum
        const float4_t cinit = {-rm, -rm, -rm, -rm};
        float4_t acc = {0.f, 0.f, 0.f, 0.f};
        #pragma unroll
        for (int mt = 0; mt < 21; ++mt) {
            half4_t kf = *(const half4_t*)&K16[(mt * 16 + l15) * 20 + qsh];
            float4_t sv = __builtin_amdgcn_mfma_f32_16x16x16f16(
                kf, qf, cinit, 0, 0, 0);
            unsigned int sh = mb[mt >> 1] >> (((mt & 1) << 4) + qsh);
            float p0 = (sh & 1u) ? __builtin_amdgcn_exp2f(sv[0]) : 0.f;
            float p1 = (sh & 2u) ? __builtin_amdgcn_exp2f(sv[1]) : 0.f;
            float p2 = (sh & 4u) ? __builtin_amdgcn_exp2f(sv[2]) : 0.f;
            float p3 = (sh & 8u) ? __builtin_amdgcn_exp2f(sv[3]) : 0.f;
            half4_t pf;
            pf[0] = (half_t)p0; pf[1] = (half_t)p1;
            pf[2] = (half_t)p2; pf[3] = (half_t)p3;
            half4_t vf = *(const half4_t*)&VT16[l15 * 344 + mt * 16 + qsh];
            acc = __builtin_amdgcn_mfma_f32_16x16x16f16(vf, pf, acc, 0, 0, 0);
        }

        // sum for row n lives in lane (quad=2).acc[0]  (ones row c=8)
        float sum = __shfl(acc[0], 32 + l15, 64);

        if (quad < 2 && n < NN) {
            float inv = 1.0f / sum;
            half4_t o;
            o[0] = (half_t)(acc[0] * inv); o[1] = (half_t)(acc[1] * inv);
            o[2] = (half_t)(acc[2] * inv); o[3] = (half_t)(acc[3] * inv);
            *(half4_t*)(ao + base + (long)n * 64 + qsh) = o;
        }
    }
}

// ---------------------------------------------------------------------------
// Kernel 3: out = gelu(ao @ W10.T + b10) @ W11.T + b11 (verbatim baseline).
// ---------------------------------------------------------------------------
__global__ __launch_bounds__(512) void proj_kernel(
    const half_t* __restrict__ ao, const half_t* __restrict__ wab,
    const float* __restrict__ b10, const float* __restrict__ b11,
    float* __restrict__ out)
{
    __shared__ __attribute__((aligned(16))) half_t a16[64 * PS];
    __shared__ __attribute__((aligned(16))) half_t wA[64 * PS];
    __shared__ __attribute__((aligned(16))) half_t wB[64 * PS];
    __shared__ __attribute__((aligned(16))) half_t h16[64 * PS];
    const int tid  = threadIdx.x;
    const int row0 = blockIdx.x * 64;

    for (int idx = tid; idx < 512; idx += 512) {
        int r = idx >> 3, c8 = idx & 7;
        int R = row0 + r;
        uint4 u = {0u, 0u, 0u, 0u};
        if (R < NROWS) u = *(const uint4*)(ao + (long)R * 64 + c8 * 8);
        *(uint4*)&a16[r * PS + c8 * 8] = u;
        *(uint4*)&wA[r * PS + c8 * 8] = *(const uint4*)&wab[r * 64 + c8 * 8];
        *(uint4*)&wB[r * PS + c8 * 8] = *(const uint4*)&wab[4096 + r * 64 + c8 * 8];
    }
    __syncthreads();

    const int lane = tid & 63, wv = tid >> 6;
    const int l15 = lane & 15, quad = lane >> 4;
    const int rbase = (wv & 3) * 16, ch = wv >> 2;

    // stage 1: h = gelu(a @ W10.T + b10)
    float4_t acc[2];
    #pragma unroll
    for (int cc = 0; cc < 2; ++cc) {
        float bias = b10[(ch * 2 + cc) * 16 + l15];
        acc[cc] = (float4_t){bias, bias, bias, bias};
    }
    #pragma unroll
    for (int kk = 0; kk < 4; ++kk) {
        half4_t a = *(const half4_t*)&a16[(rbase + l15) * PS + kk * 16 + quad * 4];
        #pragma unroll
        for (int cc = 0; cc < 2; ++cc) {
            half4_t bf = *(const half4_t*)
                &wA[((ch * 2 + cc) * 16 + l15) * PS + kk * 16 + quad * 4];
            acc[cc] = __builtin_amdgcn_mfma_f32_16x16x16f16(a, bf, acc[cc], 0, 0, 0);
        }
    }
    #pragma unroll
    for (int cc = 0; cc < 2; ++cc) {
        #pragma unroll
        for (int rr = 0; rr < 4; ++rr)
            h16[(rbase + quad * 4 + rr) * PS + (ch * 2 + cc) * 16 + l15] =
                (half_t)gelu_f(acc[cc][rr]);
    }
    __syncthreads();

    // stage 2: out = h @ W11.T + b11
    #pragma unroll
    for (int cc = 0; cc < 2; ++cc) {
        float bias = b11[(ch * 2 + cc) * 16 + l15];
        acc[cc] = (float4_t){bias, bias, bias, bias};
    }
    #pragma unroll
    for (int kk = 0; kk < 4; ++kk) {
        half4_t a = *(const half4_t*)&h16[(rbase + l15) * PS + kk * 16 + quad * 4];
        #pragma unroll
        for (int cc = 0; cc < 2; ++cc) {
            half4_t bf = *(const half4_t*)
                &wB[((ch * 2 + cc) * 16 + l15) * PS + kk * 16 + quad * 4];
            acc[cc] = __builtin_amdgcn_mfma_f32_16x16x16f16(a, bf, acc[cc], 0, 0, 0);
        }
    }
    #pragma unroll
    for (int cc = 0; cc < 2; ++cc) {
        #pragma unroll
        for (int rr = 0; rr < 4; ++rr) {
            int R = row0 + rbase + quad * 4 + rr;
            if (R < NROWS)
                out[R * 64 + (ch * 2 + cc) * 16 + l15] = acc[cc][rr];
        }
    }
}

extern "C" void kernel_launch(void* const* d_in, const int* in_sizes, int n_in,
                              void* d_out, int out_size, void* d_ws, size_t ws_size,
                              hipStream_t stream) {
    const float* X   = (const float*)d_in[0];
    const float* STE = (const float*)d_in[1];
    const int*   adj = (const int*)d_in[2];
    const float* W7  = (const float*)d_in[3];
    const float* b7  = (const float*)d_in[4];
    const float* W8  = (const float*)d_in[5];
    const float* b8  = (const float*)d_in[6];
    const float* W9  = (const float*)d_in[7];
    const float* b9  = (const float*)d_in[8];
    const float* W10 = (const float*)d_in[9];
    const float* b10 = (const float*)d_in[10];
    const float* W11 = (const float*)d_in[11];
    const float* b11 = (const float*)d_in[12];

    char* wsb = (char*)d_ws;
    const long S = (long)NROWS * 64;           // 1,996,800 elements
    half_t* qb = (half_t*)wsb;
    half_t* kb = qb + S;
    half_t* vb = qb + 2 * S;
    half_t* ab = qb + 3 * S;
    unsigned int* pk = (unsigned int*)(wsb + 4 * S * sizeof(half_t));
    half_t* wab = (half_t*)(wsb + 4 * S * sizeof(half_t) + 16384);

    qkv_kernel<<<dim3(TOT_BLKS), 512, 0, stream>>>(
        X, STE, adj, W7, b7, W8, b8, W9, b9, W10, W11,
        qb, kb, vb, pk, wab);
    attn_kernel<<<dim3(8 * BT), 512, 0, stream>>>(qb, kb, vb, pk, ab);
    proj_kernel<<<dim3((NROWS + 63) / 64), 512, 0, stream>>>(
        ab, wab, b10, b11, (float*)d_out);
}

// Round 9
// 138.384 us; speedup vs baseline: 1.1049x; 1.0018x over previous
//
#include <hip/hip_runtime.h>
#include <math.h>

#define NN 325
#define BT 96
#define NROWS (BT * NN)   // 31200
// fold softmax scale and log2(e) into q: exp(s/sqrt8) == exp2(s * SCL)
#define SCL (0.35355339059327373f * 1.4426950408889634f)
#define QKV_BLKS ((NROWS + 63) / 64)        // 488
#define PREP_ITEMS (11 * NN + 8192)         // 3575 masks + 8192 wab = 11767
#define PREP_BLKS ((PREP_ITEMS + 511) / 512) // 23
#define TOT_BLKS (QKV_BLKS + PREP_BLKS)     // 511
#define HSTR (NN * 8)                        // 2600 halfs per (bt,h) plane

typedef _Float16 half_t;
typedef half_t half8_t __attribute__((ext_vector_type(8)));
typedef half_t half4_t __attribute__((ext_vector_type(4)));
typedef half_t half2_t __attribute__((ext_vector_type(2)));
typedef float float4_t __attribute__((ext_vector_type(4)));

// Exact-enough gelu: A&S 7.1.26 rational erf (|err| <= 1.5e-7, invisible at
// f16) — ~16 insts vs libm __ocml_erf_f32's branchy ~40-60.
__device__ __forceinline__ float gelu_f(float x) {
    const float z  = 0.70710678118654752f * x;
    const float az = __builtin_fabsf(z);
    const float t  = __builtin_amdgcn_rcpf(__builtin_fmaf(0.3275911f, az, 1.0f));
    float p = __builtin_fmaf(1.061405429f, t, -1.453152027f);
    p = __builtin_fmaf(p, t, 1.421413741f);
    p = __builtin_fmaf(p, t, -0.284496736f);
    p = __builtin_fmaf(p, t, 0.254829592f);
    p *= t;
    const float e = __builtin_amdgcn_exp2f(-az * az * 1.4426950408889634f);
    float er = __builtin_fmaf(-p, e, 1.0f);
    er = __builtin_copysignf(er, z);
    return 0.5f * x * (1.0f + er);
}

#define XS 136   // half stride per 128-k row (qkv)
#define PS 72    // half stride per 64-k row (proj)

// Stage a 64x128 f32 weight matrix into LDS as f16.
__device__ __forceinline__ void qkv_stage_wf(const float* __restrict__ src,
                                             half_t* dst, int tid)
{
    #pragma unroll
    for (int idx = tid; idx < 1024; idx += 512) {
        int c = idx >> 4, g = idx & 15;
        const float4* s4 = (const float4*)&src[c * 128 + g * 8];
        float4 a = s4[0], b = s4[1];
        half8_t h;
        h[0] = (half_t)a.x; h[1] = (half_t)a.y;
        h[2] = (half_t)a.z; h[3] = (half_t)a.w;
        h[4] = (half_t)b.x; h[5] = (half_t)b.y;
        h[6] = (half_t)b.z; h[7] = (half_t)b.w;
        *(half8_t*)&dst[c * XS + g * 8] = h;
    }
}

// q/k/v are written HEAD-MAJOR: plane (bt*8+h) of [NN][8] halfs, so attn
// reads are fully dense (5.2 KB/tensor/block, zero overfetch).
__device__ __forceinline__ void qkv_compute(
    const half_t* x16, const half_t* wb, const float* __restrict__ b,
    half_t* __restrict__ outp, float oscale,
    int row0, int rbase, int ch, int l15, int quad)
{
    float4_t acc[2];
    #pragma unroll
    for (int cc = 0; cc < 2; ++cc) {
        float bias = b[(ch * 2 + cc) * 16 + l15];
        acc[cc] = (float4_t){bias, bias, bias, bias};
    }
    #pragma unroll
    for (int kk = 0; kk < 8; ++kk) {
        half4_t a = *(const half4_t*)&x16[(rbase + l15) * XS + kk * 16 + quad * 4];
        #pragma unroll
        for (int cc = 0; cc < 2; ++cc) {
            half4_t bf = *(const half4_t*)
                &wb[((ch * 2 + cc) * 16 + l15) * XS + kk * 16 + quad * 4];
            acc[cc] = __builtin_amdgcn_mfma_f32_16x16x16f16(a, bf, acc[cc], 0, 0, 0);
        }
    }
    #pragma unroll
    for (int rr = 0; rr < 4; ++rr) {
        int R = row0 + rbase + quad * 4 + rr;
        if (R < NROWS) {
            int bt = R / NN, n = R - bt * NN;   // magic-mul div by const
            #pragma unroll
            for (int cc = 0; cc < 2; ++cc) {
                int col = (ch * 2 + cc) * 16 + l15;
                outp[(long)((bt << 3) + (col >> 3)) * HSTR + n * 8 + (col & 7)] =
                    (half_t)(gelu_f(acc[cc][rr]) * oscale);
            }
        }
    }
}

// ---------------------------------------------------------------------------
// Kernel 1: q/k/v = gelu(concat(X,STE) @ W.T + b) via f16 MFMA.
// r4 ping-pong structure (best measured). Blocks [488,511): prep work.
// ---------------------------------------------------------------------------
__global__ __launch_bounds__(512) void qkv_kernel(
    const float* __restrict__ X, const float* __restrict__ STE,
    const int* __restrict__ adj,
    const float* __restrict__ W7, const float* __restrict__ b7,
    const float* __restrict__ W8, const float* __restrict__ b8,
    const float* __restrict__ W9, const float* __restrict__ b9,
    const float* __restrict__ W10, const float* __restrict__ W11,
    half_t* __restrict__ q, half_t* __restrict__ k, half_t* __restrict__ v,
    unsigned int* __restrict__ packedT, half_t* __restrict__ wab)
{
    const int tid = threadIdx.x;
    const int bx  = blockIdx.x;

    if (bx >= QKV_BLKS) {
        // ------- prep tail blocks: masks + W10/W11 f16 conversion ---------
        int idx = (bx - QKV_BLKS) * 512 + tid;
        if (idx < 11 * NN) {
            int w = idx / NN, n = idx - w * NN;
            unsigned int bits = 0u;
            #pragma unroll 8
            for (int j = 0; j < 32; ++j) {
                int m = w * 32 + j;
                if (m < NN && adj[n * NN + m] > 0) bits |= (1u << j);
            }
            packedT[w * NN + n] = bits;
        } else if (idx < PREP_ITEMS) {
            int i = idx - 11 * NN;
            int p = i >> 12, r = i & 4095;
            wab[i] = (half_t)(p ? W11[r] : W10[r]);
        }
        return;
    }

    __shared__ __attribute__((aligned(16))) half_t x16[64 * XS];
    __shared__ __attribute__((aligned(16))) half_t wbuf[2][64 * XS];
    const int row0 = bx * 64;

    // stage x = concat(X, STE) -> f16
    #pragma unroll
    for (int idx = tid; idx < 2048; idx += 512) {
        int r = idx >> 5, c4 = idx & 31;
        int R = row0 + r;
        float4 f = {0.f, 0.f, 0.f, 0.f};
        if (R < NROWS)
            f = (c4 < 16) ? *(const float4*)(X + R * 64 + c4 * 4)
                          : *(const float4*)(STE + R * 64 + (c4 - 16) * 4);
        half4_t hv;
        hv[0] = (half_t)f.x; hv[1] = (half_t)f.y;
        hv[2] = (half_t)f.z; hv[3] = (half_t)f.w;
        *(half4_t*)&x16[r * XS + c4 * 4] = hv;
    }
    qkv_stage_wf(W7, wbuf[0], tid);          // W7 (f32 -> f16 inline)
    __syncthreads();

    const int lane = tid & 63, wv = tid >> 6;
    const int l15 = lane & 15, quad = lane >> 4;
    const int rbase = (wv & 3) * 16, ch = wv >> 2;

    qkv_stage_wf(W8, wbuf[1], tid);          // W8 (overlaps phase 0)
    qkv_compute(x16, wbuf[0], b7, q, SCL, row0, rbase, ch, l15, quad);
    __syncthreads();

    qkv_stage_wf(W9, wbuf[0], tid);          // W9 (overlaps phase 1)
    qkv_compute(x16, wbuf[1], b8, k, 1.0f, row0, rbase, ch, l15, quad);
    __syncthreads();

    qkv_compute(x16, wbuf[0], b9, v, 1.0f, row0, rbase, ch, l15, quad);
}

// ---------------------------------------------------------------------------
// Kernel 2: MFMA flash attention, single-pass norm-bound + XCD swizzle +
// HEAD-MAJOR q/k/v (NEW): per-block reads are dense 5.2KB/tensor — zero
// overfetch, coalesced K staging (16B/row unit-stride) and q reads (8B/lane
// unit-stride). VT16 row-8 pre-barrier removed (predicated zeroing).
// ao stays row-major [R][64] for proj.
// ---------------------------------------------------------------------------
__global__ __launch_bounds__(512) void attn_kernel(
    const half_t* __restrict__ q16g, const half_t* __restrict__ k16g,
    const half_t* __restrict__ v16g, const unsigned int* __restrict__ packedT,
    half_t* __restrict__ ao)
{
    __shared__ __attribute__((aligned(16))) half_t K16[336 * 20]; // [m][d0..15,pad]
    __shared__ __attribute__((aligned(16))) half_t VT16[16 * 344];// [c][m]
    __shared__ float smax8[8];
    const int tid = threadIdx.x;
    const int bx  = blockIdx.x;
    const int h   = bx / BT;          // 0..7
    const int bt  = bx - h * BT;      // 0..95 ; id%8 == bt%8 -> same XCD
    const long qbase = (long)((bt << 3) + h) * HSTR;       // head-major plane
    const long baseO = (long)(bt * NN) * 64 + h * 8;       // ao (row-major)

    const half4_t z4 = {(half_t)0.f, (half_t)0.f, (half_t)0.f, (half_t)0.f};

    // zero VT16 except ones-row c=8 (disjoint -> no barrier needed between)
    for (int idx = tid; idx < 16 * 344 / 2; idx += 512)
        if (idx < 1376 || idx >= 1548)            // skip row 8 (half2 idx)
            ((half2_t*)VT16)[idx] = (half2_t)(half_t)0.f;
    for (int i = tid; i < 344; i += 512)
        VT16[8 * 344 + i] = (half_t)1.0f;

    // stage K rows (dense 16B/row) + per-row |k|^2
    float nk2 = 0.0f;
    for (int r = tid; r < 336; r += 512) {
        half4_t ka = z4, kbv = z4;
        if (r < NN) {
            ka  = *(const half4_t*)(k16g + qbase + r * 8);
            kbv = *(const half4_t*)(k16g + qbase + r * 8 + 4);
        }
        *(half4_t*)&K16[r * 20]      = ka;
        *(half4_t*)&K16[r * 20 + 4]  = kbv;
        *(half4_t*)&K16[r * 20 + 8]  = z4;
        *(half4_t*)&K16[r * 20 + 12] = z4;
        #pragma unroll
        for (int j = 0; j < 4; ++j) {
            float fa = (float)ka[j], fb = (float)kbv[j];
            nk2 = fmaf(fa, fa, nk2);
            nk2 = fmaf(fb, fb, nk2);
        }
    }

    // stage V transposed via m-pair half2 writes (rows c = 0..7)
    for (int mp = tid; mp < 168; mp += 512) {
        int m0 = 2 * mp, m1 = 2 * mp + 1;
        half4_t v0a = z4, v0b = z4, v1a = z4, v1b = z4;
        if (m0 < NN) {
            v0a = *(const half4_t*)(v16g + qbase + m0 * 8);
            v0b = *(const half4_t*)(v16g + qbase + m0 * 8 + 4);
        }
        if (m1 < NN) {
            v1a = *(const half4_t*)(v16g + qbase + m1 * 8);
            v1b = *(const half4_t*)(v16g + qbase + m1 * 8 + 4);
        }
        #pragma unroll
        for (int c = 0; c < 4; ++c) {
            half2_t p0; p0[0] = v0a[c]; p0[1] = v1a[c];
            half2_t p1; p1[0] = v0b[c]; p1[1] = v1b[c];
            *(half2_t*)&VT16[c * 344 + 2 * mp]       = p0;
            *(half2_t*)&VT16[(c + 4) * 344 + 2 * mp] = p1;
        }
    }

    // block max of |k|^2 (wave butterfly + 8-word LDS, reusing the barrier)
    #pragma unroll
    for (int off = 32; off >= 1; off >>= 1)
        nk2 = fmaxf(nk2, __shfl_xor(nk2, off, 64));
    if ((tid & 63) == 0) smax8[tid >> 6] = nk2;
    __syncthreads();

    const float maxk2 = fmaxf(
        fmaxf(fmaxf(smax8[0], smax8[1]), fmaxf(smax8[2], smax8[3])),
        fmaxf(fmaxf(smax8[4], smax8[5]), fmaxf(smax8[6], smax8[7])));

    const int lane = tid & 63;
    const int wv   = tid >> 6;     // 0..7
    const int l15  = lane & 15;
    const int quad = lane >> 4;
    const int qsh  = quad * 4;

    for (int t = wv; t < 21; t += 8) {
        const int n  = t * 16 + l15;
        const int nq = (n < NN) ? n : (NN - 1);   // clamp for global reads

        half4_t qf = z4;
        if (quad < 2)
            qf = *(const half4_t*)(q16g + qbase + (long)nq * 8 + qsh);

        // rm = |q_n| * max_m|k_m|  (upper bound on all scores for row n)
        float ssq = 0.0f;
        #pragma unroll
        for (int j = 0; j < 4; ++j) {
            float fq = (float)qf[j];
            ssq = fmaf(fq, fq, ssq);
        }
        ssq += __shfl_xor(ssq, 16, 64);
        ssq += __shfl_xor(ssq, 32, 64);
        const float rm = sqrtf(ssq * maxk2);

        // mask words: latency hides under the score MFMAs
        unsigned int mb[11];
        #pragma unroll
        for (int w = 0; w < 11; ++w) mb[w] = packedT[w * NN + nq];

        // single pass: s' = K.Q^T - rm (C-operand), p = exp2(s'), ones-row sum
        const float4_t cinit = {-rm, -rm, -rm, -rm};
        float4_t acc = {0.f, 0.f, 0.f, 0.f};
        #pragma unroll
        for (int mt = 0; mt < 21; ++mt) {
            half4_t kf = *(const half4_t*)&K16[(mt * 16 + l15) * 20 + qsh];
            float4_t sv = __builtin_amdgcn_mfma_f32_16x16x16f16(
                kf, qf, cinit, 0, 0, 0);
            unsigned int sh = mb[mt >> 1] >> (((mt & 1) << 4) + qsh);
            float p0 = (sh & 1u) ? __builtin_amdgcn_exp2f(sv[0]) : 0.f;
            float p1 = (sh & 2u) ? __builtin_amdgcn_exp2f(sv[1]) : 0.f;
            float p2 = (sh & 4u) ? __builtin_amdgcn_exp2f(sv[2]) : 0.f;
            float p3 = (sh & 8u) ? __builtin_amdgcn_exp2f(sv[3]) : 0.f;
            half4_t pf;
            pf[0] = (half_t)p0; pf[1] = (half_t)p1;
            pf[2] = (half_t)p2; pf[3] = (half_t)p3;
            half4_t vf = *(const half4_t*)&VT16[l15 * 344 + mt * 16 + qsh];
            acc = __builtin_amdgcn_mfma_f32_16x16x16f16(vf, pf, acc, 0, 0, 0);
        }

        // sum for row n lives in lane (quad=2).acc[0]  (ones row c=8)
        float sum = __shfl(acc[0], 32 + l15, 64);

        if (quad < 2 && n < NN) {
            float inv = 1.0f / sum;
            half4_t o;
            o[0] = (half_t)(acc[0] * inv); o[1] = (half_t)(acc[1] * inv);
            o[2] = (half_t)(acc[2] * inv); o[3] = (half_t)(acc[3] * inv);
            *(half4_t*)(ao + baseO + (long)n * 64 + qsh) = o;
        }
    }
}

// ---------------------------------------------------------------------------
// Kernel 3: out = gelu(ao @ W10.T + b10) @ W11.T + b11 (structure unchanged;
// gelu_f now fast-erf).
// ---------------------------------------------------------------------------
__global__ __launch_bounds__(512) void proj_kernel(
    const half_t* __restrict__ ao, const half_t* __restrict__ wab,
    const float* __restrict__ b10, const float* __restrict__ b11,
    float* __restrict__ out)
{
    __shared__ __attribute__((aligned(16))) half_t a16[64 * PS];
    __shared__ __attribute__((aligned(16))) half_t wA[64 * PS];
    __shared__ __attribute__((aligned(16))) half_t wB[64 * PS];
    __shared__ __attribute__((aligned(16))) half_t h16[64 * PS];
    const int tid  = threadIdx.x;
    const int row0 = blockIdx.x * 64;

    for (int idx = tid; idx < 512; idx += 512) {
        int r = idx >> 3, c8 = idx & 7;
        int R = row0 + r;
        uint4 u = {0u, 0u, 0u, 0u};
        if (R < NROWS) u = *(const uint4*)(ao + (long)R * 64 + c8 * 8);
        *(uint4*)&a16[r * PS + c8 * 8] = u;
        *(uint4*)&wA[r * PS + c8 * 8] = *(const uint4*)&wab[r * 64 + c8 * 8];
        *(uint4*)&wB[r * PS + c8 * 8] = *(const uint4*)&wab[4096 + r * 64 + c8 * 8];
    }
    __syncthreads();

    const int lane = tid & 63, wv = tid >> 6;
    const int l15 = lane & 15, quad = lane >> 4;
    const int rbase = (wv & 3) * 16, ch = wv >> 2;

    // stage 1: h = gelu(a @ W10.T + b10)
    float4_t acc[2];
    #pragma unroll
    for (int cc = 0; cc < 2; ++cc) {
        float bias = b10[(ch * 2 + cc) * 16 + l15];
        acc[cc] = (float4_t){bias, bias, bias, bias};
    }
    #pragma unroll
    for (int kk = 0; kk < 4; ++kk) {
        half4_t a = *(const half4_t*)&a16[(rbase + l15) * PS + kk * 16 + quad * 4];
        #pragma unroll
        for (int cc = 0; cc < 2; ++cc) {
            half4_t bf = *(const half4_t*)
                &wA[((ch * 2 + cc) * 16 + l15) * PS + kk * 16 + quad * 4];
            acc[cc] = __builtin_amdgcn_mfma_f32_16x16x16f16(a, bf, acc[cc], 0, 0, 0);
        }
    }
    #pragma unroll
    for (int cc = 0; cc < 2; ++cc) {
        #pragma unroll
        for (int rr = 0; rr < 4; ++rr)
            h16[(rbase + quad * 4 + rr) * PS + (ch * 2 + cc) * 16 + l15] =
                (half_t)gelu_f(acc[cc][rr]);
    }
    __syncthreads();

    // stage 2: out = h @ W11.T + b11
    #pragma unroll
    for (int cc = 0; cc < 2; ++cc) {
        float bias = b11[(ch * 2 + cc) * 16 + l15];
        acc[cc] = (float4_t){bias, bias, bias, bias};
    }
    #pragma unroll
    for (int kk = 0; kk < 4; ++kk) {
        half4_t a = *(const half4_t*)&h16[(rbase + l15) * PS + kk * 16 + quad * 4];
        #pragma unroll
        for (int cc = 0; cc < 2; ++cc) {
            half4_t bf = *(const half4_t*)
                &wB[((ch * 2 + cc) * 16 + l15) * PS + kk * 16 + quad * 4];
            acc[cc] = __builtin_amdgcn_mfma_f32_16x16x16f16(a, bf, acc[cc], 0, 0, 0);
        }
    }
    #pragma unroll
    for (int cc = 0; cc < 2; ++cc) {
        #pragma unroll
        for (int rr = 0; rr < 4; ++rr) {
            int R = row0 + rbase + quad * 4 + rr;
            if (R < NROWS)
                out[R * 64 + (ch * 2 + cc) * 16 + l15] = acc[cc][rr];
        }
    }
}

extern "C" void kernel_launch(void* const* d_in, const int* in_sizes, int n_in,
                              void* d_out, int out_size, void* d_ws, size_t ws_size,
                              hipStream_t stream) {
    const float* X   = (const float*)d_in[0];
    const float* STE = (const float*)d_in[1];
    const int*   adj = (const int*)d_in[2];
    const float* W7  = (const float*)d_in[3];
    const float* b7  = (const float*)d_in[4];
    const float* W8  = (const float*)d_in[5];
    const float* b8  = (const float*)d_in[6];
    const float* W9  = (const float*)d_in[7];
    const float* b9  = (const float*)d_in[8];
    const float* W10 = (const float*)d_in[9];
    const float* b10 = (const float*)d_in[10];
    const float* W11 = (const float*)d_in[11];
    const float* b11 = (const float*)d_in[12];

    char* wsb = (char*)d_ws;
    const long S = (long)NROWS * 64;           // 1,996,800 elements
    half_t* qb = (half_t*)wsb;
    half_t* kb = qb + S;
    half_t* vb = qb + 2 * S;
    half_t* ab = qb + 3 * S;
    unsigned int* pk = (unsigned int*)(wsb + 4 * S * sizeof(half_t));
    half_t* wab = (half_t*)(wsb + 4 * S * sizeof(half_t) + 16384);

    qkv_kernel<<<dim3(TOT_BLKS), 512, 0, stream>>>(
        X, STE, adj, W7, b7, W8, b8, W9, b9, W10, W11,
        qb, kb, vb, pk, wab);
    attn_kernel<<<dim3(8 * BT), 512, 0, stream>>>(qb, kb, vb, pk, ab);
    proj_kernel<<<dim3((NROWS + 63) / 64), 512, 0, stream>>>(
        ab, wab, b10, b11, (float*)d_out);
}